// Round 1
// baseline (1053.664 us; speedup 1.0000x reference)
//
#include <hip/hip_runtime.h>
#include <hip/hip_bf16.h>

#define D_MODEL 512
#define N_HEADS 8
#define HDIM 64
#define D_FF 2048
#define BATCH 64
#define SEQ 500
#define MROWS (BATCH * SEQ)  // 32000, divisible by 128

typedef __attribute__((ext_vector_type(8))) short bhalf8;   // 8 bf16 = 4 VGPRs
typedef __attribute__((ext_vector_type(4))) float floatx4;  // MFMA accumulator

#define AS_GLOBAL __attribute__((address_space(1)))
#define AS_LDS __attribute__((address_space(3)))

__device__ __forceinline__ void glds16(const void* g, void* l) {
  __builtin_amdgcn_global_load_lds((const AS_GLOBAL unsigned int*)g,
                                   (AS_LDS unsigned int*)l, 16, 0, 0);
}

// ---------------------------------------------------------------------------
// LayerNorm: one block per row of 512. Optionally writes bf16 copy (for MFMA A).
// ---------------------------------------------------------------------------
template <bool WRITE_BF16>
__global__ __launch_bounds__(256) void ln_kernel(const float* __restrict__ x,
                                                 const float* __restrict__ g,
                                                 const float* __restrict__ b,
                                                 float* __restrict__ yf,
                                                 __hip_bfloat16* __restrict__ yb) {
  int row = blockIdx.x;
  int t = threadIdx.x;
  const float2* xp = (const float2*)(x + (size_t)row * D_MODEL);
  float2 v = xp[t];
  float s = v.x + v.y;
  float sq = v.x * v.x + v.y * v.y;
#pragma unroll
  for (int off = 32; off > 0; off >>= 1) {
    s += __shfl_down(s, off, 64);
    sq += __shfl_down(sq, off, 64);
  }
  __shared__ float red[8];
  if ((t & 63) == 0) {
    red[(t >> 6) * 2] = s;
    red[(t >> 6) * 2 + 1] = sq;
  }
  __syncthreads();
  s = red[0] + red[2] + red[4] + red[6];
  sq = red[1] + red[3] + red[5] + red[7];
  float mean = s * (1.0f / 512.0f);
  float var = sq * (1.0f / 512.0f) - mean * mean;
  float r = rsqrtf(var + 1e-6f);
  float2 gg = ((const float2*)g)[t];
  float2 bb = ((const float2*)b)[t];
  float y0 = (v.x - mean) * r * gg.x + bb.x;
  float y1 = (v.y - mean) * r * gg.y + bb.y;
  ((float2*)(yf + (size_t)row * D_MODEL))[t] = make_float2(y0, y1);
  if constexpr (WRITE_BF16) {
    __hip_bfloat162 bv2;
    bv2.x = __float2bfloat16(y0);
    bv2.y = __float2bfloat16(y1);
    ((__hip_bfloat162*)(yb + (size_t)row * D_MODEL))[t] = bv2;
  }
}

// ---------------------------------------------------------------------------
// Transpose + convert fp32 W[K][N] -> bf16 Wt[N][K] (LDS-tiled, 32x32)
// ---------------------------------------------------------------------------
__global__ __launch_bounds__(256) void transpose_bf16(const float* __restrict__ W,
                                                      __hip_bfloat16* __restrict__ Wt,
                                                      int K, int N) {
  __shared__ float tile[32][33];
  int n0 = blockIdx.x * 32, k0 = blockIdx.y * 32;
  int tx = threadIdx.x, ty = threadIdx.y;
#pragma unroll
  for (int j = 0; j < 32; j += 8)
    tile[ty + j][tx] = W[(size_t)(k0 + ty + j) * N + n0 + tx];
  __syncthreads();
#pragma unroll
  for (int j = 0; j < 32; j += 8)
    Wt[(size_t)(n0 + ty + j) * K + k0 + tx] = __float2bfloat16(tile[tx][ty + j]);
}

// ---------------------------------------------------------------------------
// Causal self-attention with q=k=v=h. One wave per (batch*head, 64-query tile).
// Each thread owns one query row: q[64], o[64] in regs; 64-key tiles in LDS.
// Writes hres = h + attn_out.
// ---------------------------------------------------------------------------
__global__ __launch_bounds__(64, 2) void attn_kernel(const float* __restrict__ h,
                                                     float* __restrict__ hres) {
  int blk = blockIdx.x;
  int qt = blk & 7;     // 8 query tiles of 64 (covers 500)
  int bh = blk >> 3;
  int b = bh >> 3;
  int hd = bh & 7;
  const float* base = h + (size_t)b * SEQ * D_MODEL + hd * HDIM;
  int t = threadIdx.x;
  int q_idx = qt * 64 + t;
  bool qvalid = q_idx < SEQ;

  float q[64];
  if (qvalid) {
    const float4* qp = (const float4*)(base + (size_t)q_idx * D_MODEL);
#pragma unroll
    for (int d4 = 0; d4 < 16; ++d4) {
      float4 v = qp[d4];
      q[d4 * 4 + 0] = v.x; q[d4 * 4 + 1] = v.y;
      q[d4 * 4 + 2] = v.z; q[d4 * 4 + 3] = v.w;
    }
  }
  __shared__ float kv[64][64];  // K tile == V tile (q=k=v)
  float o[64];
#pragma unroll
  for (int d = 0; d < 64; ++d) o[d] = 0.f;
  float m = -INFINITY, l = 0.f;

  for (int kt = 0; kt <= qt; ++kt) {
    __syncthreads();  // previous tile's readers done
#pragma unroll
    for (int it = 0; it < 16; ++it) {
      int e4 = it * 64 + t;
      int row = e4 >> 4;
      int c4 = e4 & 15;
      int kidx = kt * 64 + row;
      float4 v = make_float4(0.f, 0.f, 0.f, 0.f);
      if (kidx < SEQ) v = *(const float4*)(base + (size_t)kidx * D_MODEL + c4 * 4);
      ((float4*)kv)[e4] = v;
    }
    __syncthreads();

    if (qvalid) {
      int kmax = q_idx - kt * 64 + 1;  // causal bound within tile
      if (kmax > 64) kmax = 64;
      for (int i0 = 0; i0 < kmax; i0 += 8) {
        float sc[8];
#pragma unroll
        for (int j = 0; j < 8; ++j) {
          const float4* kr = (const float4*)kv[i0 + j];
          float s0 = 0, s1 = 0, s2 = 0, s3 = 0;
#pragma unroll
          for (int d4 = 0; d4 < 16; ++d4) {
            float4 kk = kr[d4];
            s0 += q[d4 * 4 + 0] * kk.x;
            s1 += q[d4 * 4 + 1] * kk.y;
            s2 += q[d4 * 4 + 2] * kk.z;
            s3 += q[d4 * 4 + 3] * kk.w;
          }
          float s = (s0 + s1) + (s2 + s3);
          sc[j] = (i0 + j < kmax) ? s * 0.125f : -INFINITY;
        }
        float cmax = sc[0];
#pragma unroll
        for (int j = 1; j < 8; ++j) cmax = fmaxf(cmax, sc[j]);
        if (cmax > m) {  // rescale only on new max (rare after warmup)
          float scale = __expf(m - cmax);
#pragma unroll
          for (int d = 0; d < 64; ++d) o[d] *= scale;
          l *= scale;
          m = cmax;
        }
        float p[8], ps = 0.f;
#pragma unroll
        for (int j = 0; j < 8; ++j) {
          p[j] = __expf(sc[j] - m);
          ps += p[j];
        }
        l += ps;
#pragma unroll
        for (int j = 0; j < 8; ++j) {
          const float4* kr = (const float4*)kv[i0 + j];
          float pj = p[j];
#pragma unroll
          for (int d4 = 0; d4 < 16; ++d4) {
            float4 kk = kr[d4];
            o[d4 * 4 + 0] += pj * kk.x;
            o[d4 * 4 + 1] += pj * kk.y;
            o[d4 * 4 + 2] += pj * kk.z;
            o[d4 * 4 + 3] += pj * kk.w;
          }
        }
      }
    }
  }

  if (qvalid) {
    float inv = 1.0f / l;
    const float4* ip = (const float4*)(base + (size_t)q_idx * D_MODEL);
    float4* op = (float4*)(hres + ((size_t)b * SEQ + q_idx) * D_MODEL + hd * HDIM);
#pragma unroll
    for (int d4 = 0; d4 < 16; ++d4) {
      float4 hv = ip[d4];
      op[d4] = make_float4(hv.x + o[d4 * 4 + 0] * inv, hv.y + o[d4 * 4 + 1] * inv,
                           hv.z + o[d4 * 4 + 2] * inv, hv.w + o[d4 * 4 + 3] * inv);
    }
  }
}

// ---------------------------------------------------------------------------
// bf16 MFMA GEMM, C = A[M,K] * Bt[N,K]^T  (m97 structure: 128x128 tile, BK=32,
// 4 waves each computing 64x64 via 4x4 frags of 16x16x32, global_load_lds w=16)
// EPI==1: out_bf16 = relu(acc + bias)       (GEMM1 -> u)
// EPI==2: out_f32 += acc + bias             (GEMM2 -> d_out, resid pre-written)
// ---------------------------------------------------------------------------
template <int EPI>
__global__ __launch_bounds__(256) void gemm_bt(const unsigned short* __restrict__ A,
                                               const unsigned short* __restrict__ Bt,
                                               const float* __restrict__ bias,
                                               float* __restrict__ outf,
                                               __hip_bfloat16* __restrict__ outb,
                                               int M, int N, int K) {
  __shared__ unsigned short As[128 * 32];  // [row 128][k 32] linear
  __shared__ unsigned short Bs[128 * 32];  // [ncol 128][k 32] linear
  int tid = threadIdx.x;
  int m0 = blockIdx.y * 128, n0 = blockIdx.x * 128;
  int lane = tid & 63;
  int w = tid >> 6;
  int wr = (w >> 1) * 64, wc = (w & 1) * 64;
  int fr = lane & 15;  // fragment row/col within 16
  int kg = lane >> 4;  // k-group 0..3 (8 contiguous k each)

  floatx4 acc[4][4];
  floatx4 zero = {0.f, 0.f, 0.f, 0.f};
#pragma unroll
  for (int i = 0; i < 4; ++i)
#pragma unroll
    for (int j = 0; j < 4; ++j) acc[i][j] = zero;

  int arow = tid >> 2;           // staging row 0..63 (it=0), +64 (it=1)
  int acol = (tid & 3) * 8;      // k offset within BK
  const unsigned short* Ag = A + (size_t)(m0 + arow) * K + acol;
  const unsigned short* Bg = Bt + (size_t)(n0 + arow) * K + acol;
  char* AsB = (char*)As;
  char* BsB = (char*)Bs;
  int wb = w * 1024;  // wave-uniform LDS base (lane*16 added by HW)

  const bhalf8* As8 = (const bhalf8*)As;
  const bhalf8* Bs8 = (const bhalf8*)Bs;
  int nk = K >> 5;
  for (int kt = 0; kt < nk; ++kt) {
    const unsigned short* ag = Ag + kt * 32;
    const unsigned short* bg = Bg + kt * 32;
    glds16(ag, AsB + wb);
    glds16(ag + (size_t)64 * K, AsB + 4096 + wb);
    glds16(bg, BsB + wb);
    glds16(bg + (size_t)64 * K, BsB + 4096 + wb);
    __syncthreads();  // drains vmcnt -> tiles ready

    bhalf8 av[4], bv[4];
#pragma unroll
    for (int mm = 0; mm < 4; ++mm) av[mm] = As8[(wr + mm * 16 + fr) * 4 + kg];
#pragma unroll
    for (int nn = 0; nn < 4; ++nn) bv[nn] = Bs8[(wc + nn * 16 + fr) * 4 + kg];
#pragma unroll
    for (int mm = 0; mm < 4; ++mm)
#pragma unroll
      for (int nn = 0; nn < 4; ++nn)
        acc[mm][nn] = __builtin_amdgcn_mfma_f32_16x16x32_bf16(av[mm], bv[nn],
                                                              acc[mm][nn], 0, 0, 0);
    __syncthreads();  // readers done before next stage overwrites
  }

  // C/D layout (verified m89/m91): col = lane&15, row = (lane>>4)*4 + reg
#pragma unroll
  for (int mm = 0; mm < 4; ++mm) {
    int gr0 = m0 + wr + mm * 16 + kg * 4;
#pragma unroll
    for (int nn = 0; nn < 4; ++nn) {
      int gc = n0 + wc + nn * 16 + fr;
      float bi = bias[gc];
#pragma unroll
      for (int j = 0; j < 4; ++j) {
        int gr = gr0 + j;
        float v = acc[mm][nn][j] + bi;
        if (EPI == 1) {
          v = v > 0.f ? v : 0.f;
          outb[(size_t)gr * N + gc] = __float2bfloat16(v);
        } else {
          size_t idx = (size_t)gr * N + gc;
          outf[idx] = outf[idx] + v;
        }
      }
    }
  }
}

// ---------------------------------------------------------------------------
extern "C" void kernel_launch(void* const* d_in, const int* in_sizes, int n_in,
                              void* d_out, int out_size, void* d_ws, size_t ws_size,
                              hipStream_t stream) {
  const float* x = (const float*)d_in[0];
  const float* ln1g = (const float*)d_in[1];
  const float* ln1b = (const float*)d_in[2];
  const float* ln2g = (const float*)d_in[3];
  const float* ln2b = (const float*)d_in[4];
  const float* W1 = (const float*)d_in[5];
  const float* b1 = (const float*)d_in[6];
  const float* W2 = (const float*)d_in[7];
  const float* b2 = (const float*)d_in[8];
  float* out = (float*)d_out;

  // Workspace layout (bytes); hres aliases first 65.5MB of u (dead by GEMM1):
  //   h:    [0, 65536000)              f32 [32000][512]
  //   u:    [65536000, 196608000)      bf16 [32000][2048]  (hres f32 aliases start)
  //   h2b:  [196608000, 229376000)     bf16 [32000][512]
  //   W1t:  [229376000, 231473152)     bf16 [2048][512]
  //   W2t:  [231473152, 233570304)     bf16 [512][2048]
  char* ws = (char*)d_ws;
  float* h = (float*)ws;
  float* hres = (float*)(ws + 65536000);
  __hip_bfloat16* u = (__hip_bfloat16*)(ws + 65536000);
  __hip_bfloat16* h2b = (__hip_bfloat16*)(ws + 196608000);
  __hip_bfloat16* W1t = (__hip_bfloat16*)(ws + 229376000);
  __hip_bfloat16* W2t = (__hip_bfloat16*)(ws + 231473152);

  // W1[512][2048] -> W1t[2048][512]; W2[2048][512] -> W2t[512][2048]
  transpose_bf16<<<dim3(D_FF / 32, D_MODEL / 32), dim3(32, 8), 0, stream>>>(
      W1, W1t, D_MODEL, D_FF);
  transpose_bf16<<<dim3(D_MODEL / 32, D_FF / 32), dim3(32, 8), 0, stream>>>(
      W2, W2t, D_FF, D_MODEL);

  ln_kernel<false><<<MROWS, 256, 0, stream>>>(x, ln1g, ln1b, h, nullptr);

  attn_kernel<<<512 * 8, 64, 0, stream>>>(h, hres);

  // h2 (f32) goes straight into d_out; GEMM2 accumulates on top of it.
  ln_kernel<true><<<MROWS, 256, 0, stream>>>(hres, ln2g, ln2b, out, h2b);

  gemm_bt<1><<<dim3(D_FF / 128, MROWS / 128), 256, 0, stream>>>(
      (const unsigned short*)h2b, (const unsigned short*)W1t, b1, nullptr, u,
      MROWS, D_FF, D_MODEL);
  gemm_bt<2><<<dim3(D_MODEL / 128, MROWS / 128), 256, 0, stream>>>(
      (const unsigned short*)u, (const unsigned short*)W2t, b2, out, nullptr,
      MROWS, D_MODEL, D_FF);
}

// Round 2
// 485.888 us; speedup vs baseline: 2.1685x; 2.1685x over previous
//
#include <hip/hip_runtime.h>
#include <hip/hip_bf16.h>

#define D_MODEL 512
#define N_HEADS 8
#define HDIM 64
#define D_FF 2048
#define BATCH 64
#define SEQ 500
#define MROWS (BATCH * SEQ)  // 32000, divisible by 128

typedef __attribute__((ext_vector_type(8))) short bhalf8;   // 8 bf16 = 4 VGPRs
typedef __attribute__((ext_vector_type(4))) float floatx4;  // MFMA accumulator

#define AS_GLOBAL __attribute__((address_space(1)))
#define AS_LDS __attribute__((address_space(3)))

__device__ __forceinline__ void glds16(const void* g, void* l) {
  __builtin_amdgcn_global_load_lds((const AS_GLOBAL unsigned int*)g,
                                   (AS_LDS unsigned int*)l, 16, 0, 0);
}

__device__ __forceinline__ unsigned short f2bf(float f) {
  __hip_bfloat16 b = __float2bfloat16(f);
  return *reinterpret_cast<unsigned short*>(&b);
}

// ---------------------------------------------------------------------------
// LayerNorm: one block per row of 512. Optionally writes bf16 copy (for MFMA A).
// ---------------------------------------------------------------------------
template <bool WRITE_BF16>
__global__ __launch_bounds__(256) void ln_kernel(const float* __restrict__ x,
                                                 const float* __restrict__ g,
                                                 const float* __restrict__ b,
                                                 float* __restrict__ yf,
                                                 __hip_bfloat16* __restrict__ yb) {
  int row = blockIdx.x;
  int t = threadIdx.x;
  const float2* xp = (const float2*)(x + (size_t)row * D_MODEL);
  float2 v = xp[t];
  float s = v.x + v.y;
  float sq = v.x * v.x + v.y * v.y;
#pragma unroll
  for (int off = 32; off > 0; off >>= 1) {
    s += __shfl_down(s, off, 64);
    sq += __shfl_down(sq, off, 64);
  }
  __shared__ float red[8];
  if ((t & 63) == 0) {
    red[(t >> 6) * 2] = s;
    red[(t >> 6) * 2 + 1] = sq;
  }
  __syncthreads();
  s = red[0] + red[2] + red[4] + red[6];
  sq = red[1] + red[3] + red[5] + red[7];
  float mean = s * (1.0f / 512.0f);
  float var = sq * (1.0f / 512.0f) - mean * mean;
  float r = rsqrtf(var + 1e-6f);
  float2 gg = ((const float2*)g)[t];
  float2 bb = ((const float2*)b)[t];
  float y0 = (v.x - mean) * r * gg.x + bb.x;
  float y1 = (v.y - mean) * r * gg.y + bb.y;
  ((float2*)(yf + (size_t)row * D_MODEL))[t] = make_float2(y0, y1);
  if constexpr (WRITE_BF16) {
    __hip_bfloat162 bv2;
    bv2.x = __float2bfloat16(y0);
    bv2.y = __float2bfloat16(y1);
    ((__hip_bfloat162*)(yb + (size_t)row * D_MODEL))[t] = bv2;
  }
}

// ---------------------------------------------------------------------------
// Transpose + convert fp32 W[K][N] -> bf16 Wt[N][K] (LDS-tiled, 32x32)
// ---------------------------------------------------------------------------
__global__ __launch_bounds__(256) void transpose_bf16(const float* __restrict__ W,
                                                      __hip_bfloat16* __restrict__ Wt,
                                                      int K, int N) {
  __shared__ float tile[32][33];
  int n0 = blockIdx.x * 32, k0 = blockIdx.y * 32;
  int tx = threadIdx.x, ty = threadIdx.y;
#pragma unroll
  for (int j = 0; j < 32; j += 8)
    tile[ty + j][tx] = W[(size_t)(k0 + ty + j) * N + n0 + tx];
  __syncthreads();
#pragma unroll
  for (int j = 0; j < 32; j += 8)
    Wt[(size_t)(n0 + ty + j) * K + k0 + tx] = __float2bfloat16(tile[tx][ty + j]);
}

// ---------------------------------------------------------------------------
// MFMA flash attention, q=k=v=h (bf16 copy hb). One block = (b, head, 64-q tile),
// 4 waves x 16 query rows. 64-key tiles: K in LDS (XOR-swizzled via pre-swizzled
// global_load_lds source), V^T in LDS (reg-staged transpose, stride 72),
// P per-wave in LDS (stride 72). Online softmax, all lanes active.
// Writes hres = h + attn_out (f32).
// ---------------------------------------------------------------------------
__global__ __launch_bounds__(256) void attn_mfma(const __hip_bfloat16* __restrict__ hbp,
                                                 const float* __restrict__ h,
                                                 float* __restrict__ hres) {
  __shared__ unsigned short Ks[64 * 64];      // [key][d] 128B rows, 16B-block XOR-swizzled
  __shared__ unsigned short Vt[64 * 72];      // [d][key], stride 72 elems (144B)
  __shared__ unsigned short Ps[4 * 16 * 72];  // per-wave P [qrow][key], stride 72

  int blk = blockIdx.x;
  int qt = blk & 7;          // query tile (fast index: balances causal work)
  int bh = blk >> 3;
  int b = bh >> 3;
  int hd = bh & 7;
  int tid = threadIdx.x;
  int w = tid >> 6;
  int lane = tid & 63;
  int fr = lane & 15;        // fragment row (A: q-row / B: key / V: d-row)
  int kg = lane >> 4;        // k-group (8 contiguous k)
  int swz = (lane & 7) ^ (lane >> 3);  // pre-swizzled source col-block for K staging

  const unsigned short* hb = (const unsigned short*)hbp;
  size_t bbase = (size_t)b * SEQ * D_MODEL + hd * HDIM;

  // Q fragments in registers: wave w rows qt*64 + w*16 + fr
  int q_frag_row = qt * 64 + w * 16 + fr;
  int qr = q_frag_row < SEQ ? q_frag_row : SEQ - 1;
  bhalf8 qf[2];
  qf[0] = *(const bhalf8*)(hb + bbase + (size_t)qr * D_MODEL + kg * 8);
  qf[1] = *(const bhalf8*)(hb + bbase + (size_t)qr * D_MODEL + 32 + kg * 8);

  floatx4 O[4];
  float m[4], l[4];
#pragma unroll
  for (int nf = 0; nf < 4; ++nf) O[nf] = (floatx4){0.f, 0.f, 0.f, 0.f};
#pragma unroll
  for (int j = 0; j < 4; ++j) { m[j] = -INFINITY; l[j] = 0.f; }

  for (int kt = 0; kt <= qt; ++kt) {
    __syncthreads();  // prior iter's K/Vt readers done

    // --- stage K tile: wave w rows w*16..w*16+15, source col-block XOR(row&7)
#pragma unroll
    for (int i = 0; i < 2; ++i) {
      int drow = w * 16 + i * 8 + (lane >> 3);
      int srow = kt * 64 + drow;
      if (srow >= SEQ) srow = SEQ - 1;  // garbage rows are causally masked
      glds16(hb + bbase + (size_t)srow * D_MODEL + swz * 8,
             (char*)Ks + (w * 16 + i * 8) * 128);
    }
    // --- stage V^T: wave w covers d-cols w*16..+15, all 64 keys (lane = key)
    {
      int vrow = kt * 64 + lane;
      if (vrow >= SEQ) vrow = SEQ - 1;  // multiplied by p=0 (masked)
      bhalf8 v0 = *(const bhalf8*)(hb + bbase + (size_t)vrow * D_MODEL + w * 16);
      bhalf8 v1 = *(const bhalf8*)(hb + bbase + (size_t)vrow * D_MODEL + w * 16 + 8);
#pragma unroll
      for (int i = 0; i < 8; ++i) Vt[(w * 16 + i) * 72 + lane] = (unsigned short)v0[i];
#pragma unroll
      for (int i = 0; i < 8; ++i) Vt[(w * 16 + 8 + i) * 72 + lane] = (unsigned short)v1[i];
    }
    __syncthreads();

    // --- S = Q @ K^T (rows = wave's 16 queries, cols = 64 keys)
    floatx4 S[4];
#pragma unroll
    for (int nf = 0; nf < 4; ++nf) S[nf] = (floatx4){0.f, 0.f, 0.f, 0.f};
#pragma unroll
    for (int kk = 0; kk < 2; ++kk) {
#pragma unroll
      for (int nf = 0; nf < 4; ++nf) {
        int krow = nf * 16 + fr;
        bhalf8 kf = *(const bhalf8*)((const char*)Ks + krow * 128 +
                                     (((kk * 4 + kg) ^ (fr & 7)) << 4));
        S[nf] = __builtin_amdgcn_mfma_f32_16x16x32_bf16(qf[kk], kf, S[nf], 0, 0, 0);
      }
    }
    // scale + causal mask (only the diagonal tile needs masking)
#pragma unroll
    for (int nf = 0; nf < 4; ++nf)
#pragma unroll
      for (int j = 0; j < 4; ++j) S[nf][j] *= 0.125f;
    if (kt == qt) {
#pragma unroll
      for (int nf = 0; nf < 4; ++nf)
#pragma unroll
        for (int j = 0; j < 4; ++j)
          if (nf * 16 + fr > w * 16 + kg * 4 + j) S[nf][j] = -INFINITY;
    }

    // --- online softmax (rows = kg*4+j, spread over 16 lanes sharing kg)
    float mnew[4];
#pragma unroll
    for (int j = 0; j < 4; ++j)
      mnew[j] = fmaxf(fmaxf(S[0][j], S[1][j]), fmaxf(S[2][j], S[3][j]));
#pragma unroll
    for (int off = 1; off < 16; off <<= 1)
#pragma unroll
      for (int j = 0; j < 4; ++j) mnew[j] = fmaxf(mnew[j], __shfl_xor(mnew[j], off, 64));
#pragma unroll
    for (int j = 0; j < 4; ++j) {
      float mn = fmaxf(m[j], mnew[j]);
      float sc = __expf(m[j] - mn);  // m=-inf first tile -> sc=0
      m[j] = mn;
      l[j] *= sc;
#pragma unroll
      for (int nf = 0; nf < 4; ++nf) O[nf][j] *= sc;
    }
    float p[4][4], rs[4];
#pragma unroll
    for (int j = 0; j < 4; ++j) rs[j] = 0.f;
#pragma unroll
    for (int nf = 0; nf < 4; ++nf)
#pragma unroll
      for (int j = 0; j < 4; ++j) {
        p[nf][j] = __expf(S[nf][j] - m[j]);  // masked -> 0
        rs[j] += p[nf][j];
      }
#pragma unroll
    for (int off = 1; off < 16; off <<= 1)
#pragma unroll
      for (int j = 0; j < 4; ++j) rs[j] += __shfl_xor(rs[j], off, 64);
#pragma unroll
    for (int j = 0; j < 4; ++j) l[j] += rs[j];

    // --- P -> bf16 LDS (per-wave buffer, no barrier needed)
#pragma unroll
    for (int nf = 0; nf < 4; ++nf)
#pragma unroll
      for (int j = 0; j < 4; ++j)
        Ps[w * 1152 + (kg * 4 + j) * 72 + nf * 16 + fr] = f2bf(p[nf][j]);

    // --- O += P @ V
#pragma unroll
    for (int kk = 0; kk < 2; ++kk) {
      bhalf8 pf = *(const bhalf8*)((const char*)Ps + w * 2304 + fr * 144 +
                                   kk * 64 + kg * 16);
#pragma unroll
      for (int nf = 0; nf < 4; ++nf) {
        bhalf8 vf = *(const bhalf8*)((const char*)Vt + (nf * 16 + fr) * 144 +
                                     kk * 64 + kg * 16);
        O[nf] = __builtin_amdgcn_mfma_f32_16x16x32_bf16(pf, vf, O[nf], 0, 0, 0);
      }
    }
  }

  // --- write hres = h + O/l  (rows kg*4+j, cols nf*16+fr)
#pragma unroll
  for (int j = 0; j < 4; ++j) {
    int q = qt * 64 + w * 16 + kg * 4 + j;
    if (q < SEQ) {
      float inv = 1.0f / l[j];
      size_t rowoff = bbase + (size_t)q * D_MODEL;
#pragma unroll
      for (int nf = 0; nf < 4; ++nf) {
        size_t idx = rowoff + nf * 16 + fr;
        hres[idx] = h[idx] + O[nf][j] * inv;
      }
    }
  }
}

// ---------------------------------------------------------------------------
// bf16 MFMA GEMM, C = A[M,K] * Bt[N,K]^T  (m97 structure: 128x128 tile, BK=32,
// 4 waves each computing 64x64 via 4x4 frags of 16x16x32, global_load_lds w=16)
// EPI==1: out_bf16 = relu(acc + bias)       (GEMM1 -> u)
// EPI==2: out_f32 += acc + bias             (GEMM2 -> d_out, resid pre-written)
// ---------------------------------------------------------------------------
template <int EPI>
__global__ __launch_bounds__(256) void gemm_bt(const unsigned short* __restrict__ A,
                                               const unsigned short* __restrict__ Bt,
                                               const float* __restrict__ bias,
                                               float* __restrict__ outf,
                                               __hip_bfloat16* __restrict__ outb,
                                               int M, int N, int K) {
  __shared__ unsigned short As[128 * 32];  // [row 128][k 32] linear
  __shared__ unsigned short Bs[128 * 32];  // [ncol 128][k 32] linear
  int tid = threadIdx.x;
  int m0 = blockIdx.y * 128, n0 = blockIdx.x * 128;
  int lane = tid & 63;
  int w = tid >> 6;
  int wr = (w >> 1) * 64, wc = (w & 1) * 64;
  int fr = lane & 15;  // fragment row/col within 16
  int kg = lane >> 4;  // k-group 0..3 (8 contiguous k each)

  floatx4 acc[4][4];
  floatx4 zero = {0.f, 0.f, 0.f, 0.f};
#pragma unroll
  for (int i = 0; i < 4; ++i)
#pragma unroll
    for (int j = 0; j < 4; ++j) acc[i][j] = zero;

  int arow = tid >> 2;           // staging row 0..63 (it=0), +64 (it=1)
  int acol = (tid & 3) * 8;      // k offset within BK
  const unsigned short* Ag = A + (size_t)(m0 + arow) * K + acol;
  const unsigned short* Bg = Bt + (size_t)(n0 + arow) * K + acol;
  char* AsB = (char*)As;
  char* BsB = (char*)Bs;
  int wb = w * 1024;  // wave-uniform LDS base (lane*16 added by HW)

  const bhalf8* As8 = (const bhalf8*)As;
  const bhalf8* Bs8 = (const bhalf8*)Bs;
  int nk = K >> 5;
  for (int kt = 0; kt < nk; ++kt) {
    const unsigned short* ag = Ag + kt * 32;
    const unsigned short* bg = Bg + kt * 32;
    glds16(ag, AsB + wb);
    glds16(ag + (size_t)64 * K, AsB + 4096 + wb);
    glds16(bg, BsB + wb);
    glds16(bg + (size_t)64 * K, BsB + 4096 + wb);
    __syncthreads();  // drains vmcnt -> tiles ready

    bhalf8 av[4], bv[4];
#pragma unroll
    for (int mm = 0; mm < 4; ++mm) av[mm] = As8[(wr + mm * 16 + fr) * 4 + kg];
#pragma unroll
    for (int nn = 0; nn < 4; ++nn) bv[nn] = Bs8[(wc + nn * 16 + fr) * 4 + kg];
#pragma unroll
    for (int mm = 0; mm < 4; ++mm)
#pragma unroll
      for (int nn = 0; nn < 4; ++nn)
        acc[mm][nn] = __builtin_amdgcn_mfma_f32_16x16x32_bf16(av[mm], bv[nn],
                                                              acc[mm][nn], 0, 0, 0);
    __syncthreads();  // readers done before next stage overwrites
  }

  // C/D layout (verified m89/m91): col = lane&15, row = (lane>>4)*4 + reg
#pragma unroll
  for (int mm = 0; mm < 4; ++mm) {
    int gr0 = m0 + wr + mm * 16 + kg * 4;
#pragma unroll
    for (int nn = 0; nn < 4; ++nn) {
      int gc = n0 + wc + nn * 16 + fr;
      float bi = bias[gc];
#pragma unroll
      for (int j = 0; j < 4; ++j) {
        int gr = gr0 + j;
        float v = acc[mm][nn][j] + bi;
        if (EPI == 1) {
          v = v > 0.f ? v : 0.f;
          outb[(size_t)gr * N + gc] = __float2bfloat16(v);
        } else {
          size_t idx = (size_t)gr * N + gc;
          outf[idx] = outf[idx] + v;
        }
      }
    }
  }
}

// ---------------------------------------------------------------------------
extern "C" void kernel_launch(void* const* d_in, const int* in_sizes, int n_in,
                              void* d_out, int out_size, void* d_ws, size_t ws_size,
                              hipStream_t stream) {
  const float* x = (const float*)d_in[0];
  const float* ln1g = (const float*)d_in[1];
  const float* ln1b = (const float*)d_in[2];
  const float* ln2g = (const float*)d_in[3];
  const float* ln2b = (const float*)d_in[4];
  const float* W1 = (const float*)d_in[5];
  const float* b1 = (const float*)d_in[6];
  const float* W2 = (const float*)d_in[7];
  const float* b2 = (const float*)d_in[8];
  float* out = (float*)d_out;

  // Workspace layout (233,570,304 B total, same footprint as round 1):
  //   h:    [0, 65536000)              f32 [32000][512]   (LN1 out; dead after attn)
  //   h2b:  [0, 32768000)              bf16 (LN2 out; aliases dead h)
  //   hb:   [65536000, 98304000)       bf16 [32000][512]  (LN1 out bf16)
  //   hres: [98304000, 163840000)      f32 (attn out; dead after LN2)
  //   u:    [98304000, 229376000)      bf16 [32000][2048] (aliases dead hres)
  //   W1t:  [229376000, 231473152)     bf16 [2048][512]
  //   W2t:  [231473152, 233570304)     bf16 [512][2048]
  char* ws = (char*)d_ws;
  float* h = (float*)ws;
  __hip_bfloat16* h2b = (__hip_bfloat16*)ws;
  __hip_bfloat16* hb = (__hip_bfloat16*)(ws + 65536000);
  float* hres = (float*)(ws + 98304000);
  __hip_bfloat16* u = (__hip_bfloat16*)(ws + 98304000);
  __hip_bfloat16* W1t = (__hip_bfloat16*)(ws + 229376000);
  __hip_bfloat16* W2t = (__hip_bfloat16*)(ws + 231473152);

  // W1[512][2048] -> W1t[2048][512]; W2[2048][512] -> W2t[512][2048]
  transpose_bf16<<<dim3(D_FF / 32, D_MODEL / 32), dim3(32, 8), 0, stream>>>(
      W1, W1t, D_MODEL, D_FF);
  transpose_bf16<<<dim3(D_MODEL / 32, D_FF / 32), dim3(32, 8), 0, stream>>>(
      W2, W2t, D_FF, D_MODEL);

  ln_kernel<true><<<MROWS, 256, 0, stream>>>(x, ln1g, ln1b, h, hb);

  attn_mfma<<<512 * 8, 256, 0, stream>>>(hb, h, hres);

  // h2 (f32) goes straight into d_out; GEMM2 accumulates on top of it.
  ln_kernel<true><<<MROWS, 256, 0, stream>>>(hres, ln2g, ln2b, out, h2b);

  gemm_bt<1><<<dim3(D_FF / 128, MROWS / 128), 256, 0, stream>>>(
      (const unsigned short*)h2b, (const unsigned short*)W1t, b1, nullptr, u,
      MROWS, D_FF, D_MODEL);
  gemm_bt<2><<<dim3(D_MODEL / 128, MROWS / 128), 256, 0, stream>>>(
      (const unsigned short*)u, (const unsigned short*)W2t, b2, out, nullptr,
      MROWS, D_MODEL, D_FF);
}

// Round 3
// 417.076 us; speedup vs baseline: 2.5263x; 1.1650x over previous
//
#include <hip/hip_runtime.h>
#include <hip/hip_bf16.h>

#define D_MODEL 512
#define N_HEADS 8
#define HDIM 64
#define D_FF 2048
#define BATCH 64
#define SEQ 500
#define MROWS (BATCH * SEQ)  // 32000

typedef __attribute__((ext_vector_type(8))) short bhalf8;   // 8 bf16 = 4 VGPRs
typedef __attribute__((ext_vector_type(4))) float floatx4;  // MFMA accumulator

#define AS_GLOBAL __attribute__((address_space(1)))
#define AS_LDS __attribute__((address_space(3)))

__device__ __forceinline__ void glds16(const void* g, void* l) {
  __builtin_amdgcn_global_load_lds((const AS_GLOBAL unsigned int*)g,
                                   (AS_LDS unsigned int*)l, 16, 0, 0);
}

__device__ __forceinline__ unsigned short f2bf(float f) {
  __hip_bfloat16 b = __float2bfloat16(f);
  return *reinterpret_cast<unsigned short*>(&b);
}

// ---------------------------------------------------------------------------
// LayerNorm: one block per row of 512. Optionally writes bf16 copy (for MFMA A).
// ---------------------------------------------------------------------------
template <bool WRITE_BF16>
__global__ __launch_bounds__(256) void ln_kernel(const float* __restrict__ x,
                                                 const float* __restrict__ g,
                                                 const float* __restrict__ b,
                                                 float* __restrict__ yf,
                                                 __hip_bfloat16* __restrict__ yb) {
  int row = blockIdx.x;
  int t = threadIdx.x;
  const float2* xp = (const float2*)(x + (size_t)row * D_MODEL);
  float2 v = xp[t];
  float s = v.x + v.y;
  float sq = v.x * v.x + v.y * v.y;
#pragma unroll
  for (int off = 32; off > 0; off >>= 1) {
    s += __shfl_down(s, off, 64);
    sq += __shfl_down(sq, off, 64);
  }
  __shared__ float red[8];
  if ((t & 63) == 0) {
    red[(t >> 6) * 2] = s;
    red[(t >> 6) * 2 + 1] = sq;
  }
  __syncthreads();
  s = red[0] + red[2] + red[4] + red[6];
  sq = red[1] + red[3] + red[5] + red[7];
  float mean = s * (1.0f / 512.0f);
  float var = sq * (1.0f / 512.0f) - mean * mean;
  float r = rsqrtf(var + 1e-6f);
  float2 gg = ((const float2*)g)[t];
  float2 bb = ((const float2*)b)[t];
  float y0 = (v.x - mean) * r * gg.x + bb.x;
  float y1 = (v.y - mean) * r * gg.y + bb.y;
  ((float2*)(yf + (size_t)row * D_MODEL))[t] = make_float2(y0, y1);
  if constexpr (WRITE_BF16) {
    __hip_bfloat162 bv2;
    bv2.x = __float2bfloat16(y0);
    bv2.y = __float2bfloat16(y1);
    ((__hip_bfloat162*)(yb + (size_t)row * D_MODEL))[t] = bv2;
  }
}

// ---------------------------------------------------------------------------
// Transpose + convert fp32 W[K][N] -> bf16 Wt[N][K] (LDS-tiled, 32x32)
// ---------------------------------------------------------------------------
__global__ __launch_bounds__(256) void transpose_bf16(const float* __restrict__ W,
                                                      __hip_bfloat16* __restrict__ Wt,
                                                      int K, int N) {
  __shared__ float tile[32][33];
  int n0 = blockIdx.x * 32, k0 = blockIdx.y * 32;
  int tx = threadIdx.x, ty = threadIdx.y;
#pragma unroll
  for (int j = 0; j < 32; j += 8)
    tile[ty + j][tx] = W[(size_t)(k0 + ty + j) * N + n0 + tx];
  __syncthreads();
#pragma unroll
  for (int j = 0; j < 32; j += 8)
    Wt[(size_t)(n0 + ty + j) * K + k0 + tx] = __float2bfloat16(tile[tx][ty + j]);
}

// ---------------------------------------------------------------------------
// MFMA flash attention (unchanged from round 2; not a top-5 cost).
// ---------------------------------------------------------------------------
__global__ __launch_bounds__(256) void attn_mfma(const __hip_bfloat16* __restrict__ hbp,
                                                 const float* __restrict__ h,
                                                 float* __restrict__ hres) {
  __shared__ unsigned short Ks[64 * 64];
  __shared__ unsigned short Vt[64 * 72];
  __shared__ unsigned short Ps[4 * 16 * 72];

  int blk = blockIdx.x;
  int qt = blk & 7;
  int bh = blk >> 3;
  int b = bh >> 3;
  int hd = bh & 7;
  int tid = threadIdx.x;
  int w = tid >> 6;
  int lane = tid & 63;
  int fr = lane & 15;
  int kg = lane >> 4;
  int swz = (lane & 7) ^ (lane >> 3);

  const unsigned short* hb = (const unsigned short*)hbp;
  size_t bbase = (size_t)b * SEQ * D_MODEL + hd * HDIM;

  int q_frag_row = qt * 64 + w * 16 + fr;
  int qr = q_frag_row < SEQ ? q_frag_row : SEQ - 1;
  bhalf8 qf[2];
  qf[0] = *(const bhalf8*)(hb + bbase + (size_t)qr * D_MODEL + kg * 8);
  qf[1] = *(const bhalf8*)(hb + bbase + (size_t)qr * D_MODEL + 32 + kg * 8);

  floatx4 O[4];
  float m[4], l[4];
#pragma unroll
  for (int nf = 0; nf < 4; ++nf) O[nf] = (floatx4){0.f, 0.f, 0.f, 0.f};
#pragma unroll
  for (int j = 0; j < 4; ++j) { m[j] = -INFINITY; l[j] = 0.f; }

  for (int kt = 0; kt <= qt; ++kt) {
    __syncthreads();
#pragma unroll
    for (int i = 0; i < 2; ++i) {
      int srow = kt * 64 + w * 16 + i * 8 + (lane >> 3);
      if (srow >= SEQ) srow = SEQ - 1;
      glds16(hb + bbase + (size_t)srow * D_MODEL + swz * 8,
             (char*)Ks + (w * 16 + i * 8) * 128);
    }
    {
      int vrow = kt * 64 + lane;
      if (vrow >= SEQ) vrow = SEQ - 1;
      bhalf8 v0 = *(const bhalf8*)(hb + bbase + (size_t)vrow * D_MODEL + w * 16);
      bhalf8 v1 = *(const bhalf8*)(hb + bbase + (size_t)vrow * D_MODEL + w * 16 + 8);
#pragma unroll
      for (int i = 0; i < 8; ++i) Vt[(w * 16 + i) * 72 + lane] = (unsigned short)v0[i];
#pragma unroll
      for (int i = 0; i < 8; ++i) Vt[(w * 16 + 8 + i) * 72 + lane] = (unsigned short)v1[i];
    }
    __syncthreads();

    floatx4 S[4];
#pragma unroll
    for (int nf = 0; nf < 4; ++nf) S[nf] = (floatx4){0.f, 0.f, 0.f, 0.f};
#pragma unroll
    for (int kk = 0; kk < 2; ++kk) {
#pragma unroll
      for (int nf = 0; nf < 4; ++nf) {
        int krow = nf * 16 + fr;
        bhalf8 kf = *(const bhalf8*)((const char*)Ks + krow * 128 +
                                     (((kk * 4 + kg) ^ (fr & 7)) << 4));
        S[nf] = __builtin_amdgcn_mfma_f32_16x16x32_bf16(qf[kk], kf, S[nf], 0, 0, 0);
      }
    }
#pragma unroll
    for (int nf = 0; nf < 4; ++nf)
#pragma unroll
      for (int j = 0; j < 4; ++j) S[nf][j] *= 0.125f;
    if (kt == qt) {
#pragma unroll
      for (int nf = 0; nf < 4; ++nf)
#pragma unroll
        for (int j = 0; j < 4; ++j)
          if (nf * 16 + fr > w * 16 + kg * 4 + j) S[nf][j] = -INFINITY;
    }

    float mnew[4];
#pragma unroll
    for (int j = 0; j < 4; ++j)
      mnew[j] = fmaxf(fmaxf(S[0][j], S[1][j]), fmaxf(S[2][j], S[3][j]));
#pragma unroll
    for (int off = 1; off < 16; off <<= 1)
#pragma unroll
      for (int j = 0; j < 4; ++j) mnew[j] = fmaxf(mnew[j], __shfl_xor(mnew[j], off, 64));
#pragma unroll
    for (int j = 0; j < 4; ++j) {
      float mn = fmaxf(m[j], mnew[j]);
      float sc = __expf(m[j] - mn);
      m[j] = mn;
      l[j] *= sc;
#pragma unroll
      for (int nf = 0; nf < 4; ++nf) O[nf][j] *= sc;
    }
    float p[4][4], rs[4];
#pragma unroll
    for (int j = 0; j < 4; ++j) rs[j] = 0.f;
#pragma unroll
    for (int nf = 0; nf < 4; ++nf)
#pragma unroll
      for (int j = 0; j < 4; ++j) {
        p[nf][j] = __expf(S[nf][j] - m[j]);
        rs[j] += p[nf][j];
      }
#pragma unroll
    for (int off = 1; off < 16; off <<= 1)
#pragma unroll
      for (int j = 0; j < 4; ++j) rs[j] += __shfl_xor(rs[j], off, 64);
#pragma unroll
    for (int j = 0; j < 4; ++j) l[j] += rs[j];

#pragma unroll
    for (int nf = 0; nf < 4; ++nf)
#pragma unroll
      for (int j = 0; j < 4; ++j)
        Ps[w * 1152 + (kg * 4 + j) * 72 + nf * 16 + fr] = f2bf(p[nf][j]);

#pragma unroll
    for (int kk = 0; kk < 2; ++kk) {
      bhalf8 pf = *(const bhalf8*)((const char*)Ps + w * 2304 + fr * 144 +
                                   kk * 64 + kg * 16);
#pragma unroll
      for (int nf = 0; nf < 4; ++nf) {
        bhalf8 vf = *(const bhalf8*)((const char*)Vt + (nf * 16 + fr) * 144 +
                                     kk * 64 + kg * 16);
        O[nf] = __builtin_amdgcn_mfma_f32_16x16x32_bf16(pf, vf, O[nf], 0, 0, 0);
      }
    }
  }

#pragma unroll
  for (int j = 0; j < 4; ++j) {
    int q = qt * 64 + w * 16 + kg * 4 + j;
    if (q < SEQ) {
      float inv = 1.0f / l[j];
      size_t rowoff = bbase + (size_t)q * D_MODEL;
#pragma unroll
      for (int nf = 0; nf < 4; ++nf) {
        size_t idx = rowoff + nf * 16 + fr;
        hres[idx] = h[idx] + O[nf][j] * inv;
      }
    }
  }
}

// ---------------------------------------------------------------------------
// Deep-pipelined bf16 MFMA GEMM: C = A[M,K] * Bt[N,K]^T.
// 256x256 tile, BK=32, 8 waves (2M x 4N, each 128x64 out), 4 LDS buffers
// (128 KiB), stage 2 K-tiles ahead via global_load_lds w=16, counted
// s_waitcnt vmcnt(4) ONCE per K-tile (before the phase barrier, so the
// barrier propagates the per-wave guarantee block-wide), raw s_barrier
// (no vmcnt(0) drain), setprio(1) around MFMA clusters.
// LDS rows are 64B with XOR swizzle byte^=((row&3)<<4): conflict-free
// ds_read_b128 (8 slot-groups x 8 lanes tile all 32 banks). Swizzle applied
// on BOTH sides: pre-swizzled global source col + swizzled read addr.
// Race-freedom: buffer b written for tile t during tile t-2's phases; its
// previous reader (tile t-4) finished 2 barrier-separated tiles earlier.
// EPI==1: out_bf16 = relu(acc + bias)    EPI==2: out_f32 += acc + bias
// ---------------------------------------------------------------------------
template <int EPI>
__global__ __launch_bounds__(512, 2) void gemm8p(const unsigned short* __restrict__ A,
                                                 const unsigned short* __restrict__ Bt,
                                                 const float* __restrict__ bias,
                                                 float* __restrict__ outf,
                                                 __hip_bfloat16* __restrict__ outb,
                                                 int M, int N, int K, int gx) {
  __shared__ __align__(16) char smem[4 * 32768];  // [buf][A 16KB | B 16KB]

  // bijective XCD-chunked block swizzle (m204); n-fast linearization so each
  // XCD owns a row-band of A (read once) + all of B (fits 4MB L2).
  int nwg = gridDim.x;
  int bid = blockIdx.x;
  int q = nwg >> 3, r = nwg & 7;
  int xcd = bid & 7, lo = bid >> 3;
  int wg = (xcd < r ? xcd * (q + 1) : r * (q + 1) + (xcd - r) * q) + lo;
  int by = wg / gx, bx = wg % gx;
  int m0 = by * 256, n0 = bx * 256;

  int tid = threadIdx.x;
  int w = tid >> 6, lane = tid & 63;
  int wm = w >> 2, wn = w & 3;
  int fr = lane & 15, kg = lane >> 4;

  // --- staging addressing (per thread: 2 A-loads + 2 B-loads per K-tile)
  int si0 = w * 2, si1 = w * 2 + 1;                  // 1KB chunk ids 0..15
  int srow0 = si0 * 16 + (lane >> 2);
  int srow1 = si1 * 16 + (lane >> 2);
  int scol = (((lane & 3) ^ ((lane >> 2) & 3)) << 3);  // pre-swizzled source col
  const unsigned short* Asrc0 = A + (size_t)(m0 + srow0) * K + scol;
  const unsigned short* Asrc1 = A + (size_t)(m0 + srow1) * K + scol;
  const unsigned short* Bsrc0 = Bt + (size_t)(n0 + srow0) * K + scol;
  const unsigned short* Bsrc1 = Bt + (size_t)(n0 + srow1) * K + scol;
  int dA0 = si0 * 1024, dA1 = si1 * 1024;            // wave-uniform LDS dests

  // --- fragment read addressing (swizzled)
  int slot = ((kg ^ (fr & 3)) << 4);
  int aoff = wm * 8192 + fr * 64 + slot;              // + mm*1024
  int boff = 16384 + wn * 4096 + fr * 64 + slot;      // + nn*1024

  floatx4 acc[8][4];
#pragma unroll
  for (int i = 0; i < 8; ++i)
#pragma unroll
    for (int j = 0; j < 4; ++j) acc[i][j] = (floatx4){0.f, 0.f, 0.f, 0.f};

  int nt = K >> 5;

#define STAGE_A(t, buf)                                          \
  {                                                              \
    char* d = smem + (buf) * 32768;                              \
    glds16(Asrc0 + (t) * 32, d + dA0);                           \
    glds16(Asrc1 + (t) * 32, d + dA1);                           \
  }
#define STAGE_B(t, buf)                                          \
  {                                                              \
    char* d = smem + (buf) * 32768 + 16384;                      \
    glds16(Bsrc0 + (t) * 32, d + dA0);                           \
    glds16(Bsrc1 + (t) * 32, d + dA1);                           \
  }

  // prologue: tiles 0,1 in flight; wait tile 0 (per-wave), barrier propagates.
  STAGE_A(0, 0); STAGE_B(0, 0);
  STAGE_A(1, 1); STAGE_B(1, 1);
  asm volatile("s_waitcnt vmcnt(4)" ::: "memory");
  __builtin_amdgcn_s_barrier();

  for (int t = 0; t < nt; ++t) {
    const char* bufp = smem + (t & 3) * 32768;
    bhalf8 afr[4], bfr[4];

    // ---- phase 0: quadrant mq=0 (mm 0..3), load all B frags
#pragma unroll
    for (int nn = 0; nn < 4; ++nn)
      bfr[nn] = *(const bhalf8*)(bufp + boff + nn * 1024);
#pragma unroll
    for (int ml = 0; ml < 4; ++ml)
      afr[ml] = *(const bhalf8*)(bufp + aoff + ml * 1024);
    if (t + 2 < nt) STAGE_A(t + 2, (t + 2) & 3);
    __builtin_amdgcn_s_barrier();
    __builtin_amdgcn_s_setprio(1);
#pragma unroll
    for (int ml = 0; ml < 4; ++ml)
#pragma unroll
      for (int nn = 0; nn < 4; ++nn)
        acc[ml][nn] =
            __builtin_amdgcn_mfma_f32_16x16x32_bf16(afr[ml], bfr[nn], acc[ml][nn], 0, 0, 0);
    __builtin_amdgcn_s_setprio(0);
    __builtin_amdgcn_s_barrier();

    // ---- phase 1: quadrant mq=1 (mm 4..7), B frags reused
#pragma unroll
    for (int ml = 0; ml < 4; ++ml)
      afr[ml] = *(const bhalf8*)(bufp + aoff + (4 + ml) * 1024);
    if (t + 2 < nt) STAGE_B(t + 2, (t + 2) & 3);
    __builtin_amdgcn_s_barrier();
    __builtin_amdgcn_s_setprio(1);
#pragma unroll
    for (int ml = 0; ml < 4; ++ml)
#pragma unroll
      for (int nn = 0; nn < 4; ++nn)
        acc[4 + ml][nn] =
            __builtin_amdgcn_mfma_f32_16x16x32_bf16(afr[ml], bfr[nn], acc[4 + ml][nn], 0, 0, 0);
    __builtin_amdgcn_s_setprio(0);
    // counted wait: tile t+1 fully resident after the barrier (per-wave wait
    // BEFORE barrier => block-wide guarantee). Tail drains to 0.
    if (t < nt - 2)
      asm volatile("s_waitcnt vmcnt(4)" ::: "memory");
    else
      asm volatile("s_waitcnt vmcnt(0)" ::: "memory");
    __builtin_amdgcn_s_barrier();
  }
#undef STAGE_A
#undef STAGE_B

  // epilogue: C/D layout col=fr, row=kg*4+j (verified m89/m91)
  int grow_base = m0 + wm * 128 + kg * 4;
  int gcol_base = n0 + wn * 64 + fr;
#pragma unroll
  for (int mm = 0; mm < 8; ++mm) {
#pragma unroll
    for (int nn = 0; nn < 4; ++nn) {
      int gc = gcol_base + nn * 16;
      float bi = bias[gc];
#pragma unroll
      for (int j = 0; j < 4; ++j) {
        int gr = grow_base + mm * 16 + j;
        float v = acc[mm][nn][j] + bi;
        if (EPI == 1) {
          v = v > 0.f ? v : 0.f;
          outb[(size_t)gr * N + gc] = __float2bfloat16(v);
        } else {
          size_t idx = (size_t)gr * N + gc;
          outf[idx] = outf[idx] + v;
        }
      }
    }
  }
}

// ---------------------------------------------------------------------------
extern "C" void kernel_launch(void* const* d_in, const int* in_sizes, int n_in,
                              void* d_out, int out_size, void* d_ws, size_t ws_size,
                              hipStream_t stream) {
  const float* x = (const float*)d_in[0];
  const float* ln1g = (const float*)d_in[1];
  const float* ln1b = (const float*)d_in[2];
  const float* ln2g = (const float*)d_in[3];
  const float* ln2b = (const float*)d_in[4];
  const float* W1 = (const float*)d_in[5];
  const float* b1 = (const float*)d_in[6];
  const float* W2 = (const float*)d_in[7];
  const float* b2 = (const float*)d_in[8];
  float* out = (float*)d_out;

  // Workspace layout (233,570,304 B):
  //   h:    [0, 65536000)              f32 [32000][512]   (LN1 out; dead after attn)
  //   h2b:  [0, 32768000)              bf16 (LN2 out; aliases dead h)
  //   hb:   [65536000, 98304000)       bf16 [32000][512]  (LN1 out bf16)
  //   hres: [98304000, 163840000)      f32 (attn out; dead after LN2)
  //   u:    [98304000, 229376000)      bf16 [32000][2048] (aliases dead hres)
  //   W1t:  [229376000, 231473152)     bf16 [2048][512]
  //   W2t:  [231473152, 233570304)     bf16 [512][2048]
  char* ws = (char*)d_ws;
  float* h = (float*)ws;
  __hip_bfloat16* h2b = (__hip_bfloat16*)ws;
  __hip_bfloat16* hb = (__hip_bfloat16*)(ws + 65536000);
  float* hres = (float*)(ws + 98304000);
  __hip_bfloat16* u = (__hip_bfloat16*)(ws + 98304000);
  __hip_bfloat16* W1t = (__hip_bfloat16*)(ws + 229376000);
  __hip_bfloat16* W2t = (__hip_bfloat16*)(ws + 231473152);

  transpose_bf16<<<dim3(D_FF / 32, D_MODEL / 32), dim3(32, 8), 0, stream>>>(
      W1, W1t, D_MODEL, D_FF);
  transpose_bf16<<<dim3(D_MODEL / 32, D_FF / 32), dim3(32, 8), 0, stream>>>(
      W2, W2t, D_FF, D_MODEL);

  ln_kernel<true><<<MROWS, 256, 0, stream>>>(x, ln1g, ln1b, h, hb);

  attn_mfma<<<512 * 8, 256, 0, stream>>>(hb, h, hres);

  // h2 (f32) goes straight into d_out; GEMM2 accumulates on top of it.
  ln_kernel<true><<<MROWS, 256, 0, stream>>>(hres, ln2g, ln2b, out, h2b);

  // GEMM1: [32000,512] x [512,2048] -> u ; grid 125x8 = 1000 blocks (n-fast)
  gemm8p<1><<<(MROWS / 256) * (D_FF / 256), 512, 0, stream>>>(
      (const unsigned short*)h2b, (const unsigned short*)W1t, b1, nullptr, u,
      MROWS, D_FF, D_MODEL, D_FF / 256);
  // GEMM2: [32000,2048] x [2048,512] -> out (+=) ; grid 125x2 = 250 blocks
  gemm8p<2><<<(MROWS / 256) * (D_MODEL / 256), 512, 0, stream>>>(
      (const unsigned short*)u, (const unsigned short*)W2t, b2, out, nullptr,
      MROWS, D_MODEL, D_FF, D_MODEL / 256);
}

// Round 4
// 402.240 us; speedup vs baseline: 2.6195x; 1.0369x over previous
//
#include <hip/hip_runtime.h>
#include <hip/hip_bf16.h>

#define D_MODEL 512
#define N_HEADS 8
#define HDIM 64
#define D_FF 2048
#define BATCH 64
#define SEQ 500
#define MROWS (BATCH * SEQ)  // 32000

typedef __attribute__((ext_vector_type(8))) short bhalf8;   // 8 bf16 = 4 VGPRs
typedef __attribute__((ext_vector_type(4))) float floatx4;  // MFMA accumulator

#define AS_GLOBAL __attribute__((address_space(1)))
#define AS_LDS __attribute__((address_space(3)))

__device__ __forceinline__ void glds16(const void* g, void* l) {
  __builtin_amdgcn_global_load_lds((const AS_GLOBAL unsigned int*)g,
                                   (AS_LDS unsigned int*)l, 16, 0, 0);
}

__device__ __forceinline__ unsigned short f2bf(float f) {
  __hip_bfloat16 b = __float2bfloat16(f);
  return *reinterpret_cast<unsigned short*>(&b);
}

// ---------------------------------------------------------------------------
// LayerNorm: one block per row of 512. Optionally writes bf16 copy (for MFMA A).
// ---------------------------------------------------------------------------
template <bool WRITE_BF16>
__global__ __launch_bounds__(256) void ln_kernel(const float* __restrict__ x,
                                                 const float* __restrict__ g,
                                                 const float* __restrict__ b,
                                                 float* __restrict__ yf,
                                                 __hip_bfloat16* __restrict__ yb) {
  int row = blockIdx.x;
  int t = threadIdx.x;
  const float2* xp = (const float2*)(x + (size_t)row * D_MODEL);
  float2 v = xp[t];
  float s = v.x + v.y;
  float sq = v.x * v.x + v.y * v.y;
#pragma unroll
  for (int off = 32; off > 0; off >>= 1) {
    s += __shfl_down(s, off, 64);
    sq += __shfl_down(sq, off, 64);
  }
  __shared__ float red[8];
  if ((t & 63) == 0) {
    red[(t >> 6) * 2] = s;
    red[(t >> 6) * 2 + 1] = sq;
  }
  __syncthreads();
  s = red[0] + red[2] + red[4] + red[6];
  sq = red[1] + red[3] + red[5] + red[7];
  float mean = s * (1.0f / 512.0f);
  float var = sq * (1.0f / 512.0f) - mean * mean;
  float r = rsqrtf(var + 1e-6f);
  float2 gg = ((const float2*)g)[t];
  float2 bb = ((const float2*)b)[t];
  float y0 = (v.x - mean) * r * gg.x + bb.x;
  float y1 = (v.y - mean) * r * gg.y + bb.y;
  ((float2*)(yf + (size_t)row * D_MODEL))[t] = make_float2(y0, y1);
  if constexpr (WRITE_BF16) {
    __hip_bfloat162 bv2;
    bv2.x = __float2bfloat16(y0);
    bv2.y = __float2bfloat16(y1);
    ((__hip_bfloat162*)(yb + (size_t)row * D_MODEL))[t] = bv2;
  }
}

// ---------------------------------------------------------------------------
// Transpose + convert fp32 W[K][N] -> bf16 Wt[N][K] (LDS-tiled, 32x32)
// ---------------------------------------------------------------------------
__global__ __launch_bounds__(256) void transpose_bf16(const float* __restrict__ W,
                                                      __hip_bfloat16* __restrict__ Wt,
                                                      int K, int N) {
  __shared__ float tile[32][33];
  int n0 = blockIdx.x * 32, k0 = blockIdx.y * 32;
  int tx = threadIdx.x, ty = threadIdx.y;
#pragma unroll
  for (int j = 0; j < 32; j += 8)
    tile[ty + j][tx] = W[(size_t)(k0 + ty + j) * N + n0 + tx];
  __syncthreads();
#pragma unroll
  for (int j = 0; j < 32; j += 8)
    Wt[(size_t)(n0 + ty + j) * K + k0 + tx] = __float2bfloat16(tile[tx][ty + j]);
}

// ---------------------------------------------------------------------------
// MFMA flash attention v2: one block per (b, head), 8 waves x 64-query bands.
// K/V tiles staged ONCE per block per tile (vs 8x before). K via glds16 with
// XOR-swizzled source (conflict-free swizzled ds_read_b128 on QK); V^T built
// cooperatively (1 bhalf8 load + 8 ds_write_b16 per lane). Double-buffered:
// tile kt+1's loads issued before tile kt's compute; __syncthreads drains.
// Per active wave per tile: 4 mr-steps of {QK 8 MFMA, softmax, Ps, PV 8 MFMA}.
// Causal at tile level: wave w computes only kt <= w; barriers uniform.
// Writes hres = h + attn_out (f32).
// ---------------------------------------------------------------------------
__global__ __launch_bounds__(512) void attn_mfma8(const __hip_bfloat16* __restrict__ hbp,
                                                  const float* __restrict__ h,
                                                  float* __restrict__ hres) {
  __shared__ unsigned short Ks[2][64 * 64];  // [key][d], 128B rows, 16B-blk XOR swz
  __shared__ unsigned short Vt[2][64 * 72];  // [d][key], stride 72
  __shared__ unsigned short Ps[8][16 * 72];  // per-wave P slab (reused per mr)

  int blk = blockIdx.x;
  int b = blk >> 3, hd = blk & 7;
  int tid = threadIdx.x;
  int w = tid >> 6, lane = tid & 63;
  int fr = lane & 15, kg = lane >> 4;

  const unsigned short* hb = (const unsigned short*)hbp;
  size_t bbase = (size_t)b * SEQ * D_MODEL + hd * HDIM;

  // Q fragments: wave w owns q rows w*64 .. w*64+63 (4 frag-rows of 16)
  bhalf8 qf[4][2];
#pragma unroll
  for (int mr = 0; mr < 4; ++mr) {
    int qr = w * 64 + mr * 16 + fr;
    if (qr >= SEQ) qr = SEQ - 1;  // fake rows discarded at write
#pragma unroll
    for (int kk = 0; kk < 2; ++kk)
      qf[mr][kk] = *(const bhalf8*)(hb + bbase + (size_t)qr * D_MODEL + kk * 32 + kg * 8);
  }

  floatx4 O[4][4];
  float m[4][4], l[4][4];
#pragma unroll
  for (int mr = 0; mr < 4; ++mr) {
#pragma unroll
    for (int nc = 0; nc < 4; ++nc) O[mr][nc] = (floatx4){0.f, 0.f, 0.f, 0.f};
#pragma unroll
    for (int j = 0; j < 4; ++j) { m[mr][j] = -INFINITY; l[mr][j] = 0.f; }
  }

  // K staging: thread covers dest row w*8+(lane>>3), col-block lane&7; source
  // col-block pre-swizzled with (dest_row & 7) so swizzled reads un-XOR it.
  int krow = w * 8 + (lane >> 3);
  int scb = (lane & 7) ^ (lane >> 3);

  // prologue: tile 0
  {
    int sr = krow;
    if (sr >= SEQ) sr = SEQ - 1;
    glds16(hb + bbase + (size_t)sr * D_MODEL + scb * 8, (char*)Ks[0] + w * 1024);
    int vr = lane;  // tile 0: keys 0..63 all < SEQ
    bhalf8 v0 = *(const bhalf8*)(hb + bbase + (size_t)vr * D_MODEL + w * 8);
#pragma unroll
    for (int i = 0; i < 8; ++i) Vt[0][(w * 8 + i) * 72 + lane] = (unsigned short)v0[i];
  }
  __syncthreads();  // drains glds (vmcnt) + Vt writes (lgkm)

  for (int kt = 0; kt < 8; ++kt) {
    int cur = kt & 1;
    bhalf8 vnext;
    if (kt < 7) {  // issue next tile's loads before compute (latency hides)
      int sr = (kt + 1) * 64 + krow;
      if (sr >= SEQ) sr = SEQ - 1;
      glds16(hb + bbase + (size_t)sr * D_MODEL + scb * 8,
             (char*)Ks[cur ^ 1] + w * 1024);
      int vr = (kt + 1) * 64 + lane;
      if (vr >= SEQ) vr = SEQ - 1;
      vnext = *(const bhalf8*)(hb + bbase + (size_t)vr * D_MODEL + w * 8);
    }

    if (w >= kt) {  // causal: this wave's band intersects tile kt
      const char* Kb = (const char*)Ks[cur];
      const char* Vb = (const char*)Vt[cur];
      char* Pw = (char*)Ps[w];
#pragma unroll
      for (int mr = 0; mr < 4; ++mr) {
        floatx4 S[4];
#pragma unroll
        for (int nc = 0; nc < 4; ++nc) S[nc] = (floatx4){0.f, 0.f, 0.f, 0.f};
        __builtin_amdgcn_s_setprio(1);
#pragma unroll
        for (int kk = 0; kk < 2; ++kk) {
#pragma unroll
          for (int nc = 0; nc < 4; ++nc) {
            bhalf8 kf = *(const bhalf8*)(Kb + (nc * 16 + fr) * 128 +
                                         (((kk * 4 + kg) ^ (fr & 7)) << 4));
            S[nc] = __builtin_amdgcn_mfma_f32_16x16x32_bf16(qf[mr][kk], kf, S[nc], 0, 0, 0);
          }
        }
        __builtin_amdgcn_s_setprio(0);
        // causal mask on the diagonal tile (kt == w); local row/key indices
        if (kt == w) {
#pragma unroll
          for (int nc = 0; nc < 4; ++nc)
#pragma unroll
            for (int j = 0; j < 4; ++j)
              if (nc * 16 + fr > mr * 16 + kg * 4 + j) S[nc][j] = -INFINITY;
        }
        // online softmax in UNSCALED domain; 0.125 scale folded into exp arg
        float mnew[4];
#pragma unroll
        for (int j = 0; j < 4; ++j)
          mnew[j] = fmaxf(fmaxf(S[0][j], S[1][j]), fmaxf(S[2][j], S[3][j]));
#pragma unroll
        for (int off = 1; off < 16; off <<= 1)
#pragma unroll
          for (int j = 0; j < 4; ++j)
            mnew[j] = fmaxf(mnew[j], __shfl_xor(mnew[j], off, 64));
#pragma unroll
        for (int j = 0; j < 4; ++j) {
          float mn = fmaxf(m[mr][j], mnew[j]);
          float sc = __expf((m[mr][j] - mn) * 0.125f);  // first tile: exp(-inf)=0
          m[mr][j] = mn;
          l[mr][j] *= sc;
#pragma unroll
          for (int nc = 0; nc < 4; ++nc) O[mr][nc][j] *= sc;
        }
        float p[4][4], rs[4];
#pragma unroll
        for (int j = 0; j < 4; ++j) rs[j] = 0.f;
#pragma unroll
        for (int nc = 0; nc < 4; ++nc)
#pragma unroll
          for (int j = 0; j < 4; ++j) {
            p[nc][j] = __expf((S[nc][j] - m[mr][j]) * 0.125f);  // masked -> 0
            rs[j] += p[nc][j];
          }
#pragma unroll
        for (int off = 1; off < 16; off <<= 1)
#pragma unroll
          for (int j = 0; j < 4; ++j) rs[j] += __shfl_xor(rs[j], off, 64);
#pragma unroll
        for (int j = 0; j < 4; ++j) l[mr][j] += rs[j];

        // P -> bf16 per-wave LDS slab (same-wave LDS ops are in-order)
#pragma unroll
        for (int nc = 0; nc < 4; ++nc)
#pragma unroll
          for (int j = 0; j < 4; ++j)
            *(unsigned short*)(Pw + ((kg * 4 + j) * 72 + nc * 16 + fr) * 2) =
                f2bf(p[nc][j]);

        __builtin_amdgcn_s_setprio(1);
#pragma unroll
        for (int kk = 0; kk < 2; ++kk) {
          bhalf8 pf = *(const bhalf8*)(Pw + fr * 144 + kk * 64 + kg * 16);
#pragma unroll
          for (int nc = 0; nc < 4; ++nc) {
            bhalf8 vf = *(const bhalf8*)(Vb + (nc * 16 + fr) * 144 + kk * 64 + kg * 16);
            O[mr][nc] = __builtin_amdgcn_mfma_f32_16x16x32_bf16(pf, vf, O[mr][nc], 0, 0, 0);
          }
        }
        __builtin_amdgcn_s_setprio(0);
      }
    }

    if (kt < 7) {  // write-late: V^T for tile kt+1 (buffer's old readers done)
#pragma unroll
      for (int i = 0; i < 8; ++i)
        Vt[cur ^ 1][(w * 8 + i) * 72 + lane] = (unsigned short)vnext[i];
    }
    __syncthreads();  // drains glds vmcnt + Vt lgkm; next tile ready
  }

  // write hres = h + O/l  (rows w*64+mr*16+kg*4+j, cols nc*16+fr)
#pragma unroll
  for (int mr = 0; mr < 4; ++mr)
#pragma unroll
    for (int j = 0; j < 4; ++j) {
      int q = w * 64 + mr * 16 + kg * 4 + j;
      if (q < SEQ) {
        float inv = 1.0f / l[mr][j];
        size_t ro = bbase + (size_t)q * D_MODEL;
#pragma unroll
        for (int nc = 0; nc < 4; ++nc) {
          size_t idx = ro + nc * 16 + fr;
          hres[idx] = h[idx] + O[mr][nc][j] * inv;
        }
      }
    }
}

// ---------------------------------------------------------------------------
// Deep-pipelined bf16 MFMA GEMM: C = A[M,K] * Bt[N,K]^T.  (unchanged round 3)
// 256x256 tile, BK=32, 8 waves (2M x 4N), 4 LDS buffers, stage 2 K-tiles
// ahead via global_load_lds w=16, counted vmcnt(4) once per K-tile, raw
// s_barrier, setprio around MFMA, XOR-swizzled 64B LDS rows (both sides).
// EPI==1: out_bf16 = relu(acc + bias)    EPI==2: out_f32 += acc + bias
// ---------------------------------------------------------------------------
template <int EPI>
__global__ __launch_bounds__(512, 2) void gemm8p(const unsigned short* __restrict__ A,
                                                 const unsigned short* __restrict__ Bt,
                                                 const float* __restrict__ bias,
                                                 float* __restrict__ outf,
                                                 __hip_bfloat16* __restrict__ outb,
                                                 int M, int N, int K, int gx) {
  __shared__ __align__(16) char smem[4 * 32768];  // [buf][A 16KB | B 16KB]

  int nwg = gridDim.x;
  int bid = blockIdx.x;
  int q = nwg >> 3, r = nwg & 7;
  int xcd = bid & 7, lo = bid >> 3;
  int wg = (xcd < r ? xcd * (q + 1) : r * (q + 1) + (xcd - r) * q) + lo;
  int by = wg / gx, bx = wg % gx;
  int m0 = by * 256, n0 = bx * 256;

  int tid = threadIdx.x;
  int w = tid >> 6, lane = tid & 63;
  int wm = w >> 2, wn = w & 3;
  int fr = lane & 15, kg = lane >> 4;

  int si0 = w * 2, si1 = w * 2 + 1;
  int srow0 = si0 * 16 + (lane >> 2);
  int srow1 = si1 * 16 + (lane >> 2);
  int scol = (((lane & 3) ^ ((lane >> 2) & 3)) << 3);
  const unsigned short* Asrc0 = A + (size_t)(m0 + srow0) * K + scol;
  const unsigned short* Asrc1 = A + (size_t)(m0 + srow1) * K + scol;
  const unsigned short* Bsrc0 = Bt + (size_t)(n0 + srow0) * K + scol;
  const unsigned short* Bsrc1 = Bt + (size_t)(n0 + srow1) * K + scol;
  int dA0 = si0 * 1024, dA1 = si1 * 1024;

  int slot = ((kg ^ (fr & 3)) << 4);
  int aoff = wm * 8192 + fr * 64 + slot;
  int boff = 16384 + wn * 4096 + fr * 64 + slot;

  floatx4 acc[8][4];
#pragma unroll
  for (int i = 0; i < 8; ++i)
#pragma unroll
    for (int j = 0; j < 4; ++j) acc[i][j] = (floatx4){0.f, 0.f, 0.f, 0.f};

  int nt = K >> 5;

#define STAGE_A(t, buf)                                          \
  {                                                              \
    char* d = smem + (buf) * 32768;                              \
    glds16(Asrc0 + (t) * 32, d + dA0);                           \
    glds16(Asrc1 + (t) * 32, d + dA1);                           \
  }
#define STAGE_B(t, buf)                                          \
  {                                                              \
    char* d = smem + (buf) * 32768 + 16384;                      \
    glds16(Bsrc0 + (t) * 32, d + dA0);                           \
    glds16(Bsrc1 + (t) * 32, d + dA1);                           \
  }

  STAGE_A(0, 0); STAGE_B(0, 0);
  STAGE_A(1, 1); STAGE_B(1, 1);
  asm volatile("s_waitcnt vmcnt(4)" ::: "memory");
  __builtin_amdgcn_s_barrier();

  for (int t = 0; t < nt; ++t) {
    const char* bufp = smem + (t & 3) * 32768;
    bhalf8 afr[4], bfr[4];

#pragma unroll
    for (int nn = 0; nn < 4; ++nn)
      bfr[nn] = *(const bhalf8*)(bufp + boff + nn * 1024);
#pragma unroll
    for (int ml = 0; ml < 4; ++ml)
      afr[ml] = *(const bhalf8*)(bufp + aoff + ml * 1024);
    if (t + 2 < nt) STAGE_A(t + 2, (t + 2) & 3);
    __builtin_amdgcn_s_barrier();
    __builtin_amdgcn_s_setprio(1);
#pragma unroll
    for (int ml = 0; ml < 4; ++ml)
#pragma unroll
      for (int nn = 0; nn < 4; ++nn)
        acc[ml][nn] =
            __builtin_amdgcn_mfma_f32_16x16x32_bf16(afr[ml], bfr[nn], acc[ml][nn], 0, 0, 0);
    __builtin_amdgcn_s_setprio(0);
    __builtin_amdgcn_s_barrier();

#pragma unroll
    for (int ml = 0; ml < 4; ++ml)
      afr[ml] = *(const bhalf8*)(bufp + aoff + (4 + ml) * 1024);
    if (t + 2 < nt) STAGE_B(t + 2, (t + 2) & 3);
    __builtin_amdgcn_s_barrier();
    __builtin_amdgcn_s_setprio(1);
#pragma unroll
    for (int ml = 0; ml < 4; ++ml)
#pragma unroll
      for (int nn = 0; nn < 4; ++nn)
        acc[4 + ml][nn] =
            __builtin_amdgcn_mfma_f32_16x16x32_bf16(afr[ml], bfr[nn], acc[4 + ml][nn], 0, 0, 0);
    __builtin_amdgcn_s_setprio(0);
    if (t < nt - 2)
      asm volatile("s_waitcnt vmcnt(4)" ::: "memory");
    else
      asm volatile("s_waitcnt vmcnt(0)" ::: "memory");
    __builtin_amdgcn_s_barrier();
  }
#undef STAGE_A
#undef STAGE_B

  int grow_base = m0 + wm * 128 + kg * 4;
  int gcol_base = n0 + wn * 64 + fr;
#pragma unroll
  for (int mm = 0; mm < 8; ++mm) {
#pragma unroll
    for (int nn = 0; nn < 4; ++nn) {
      int gc = gcol_base + nn * 16;
      float bi = bias[gc];
#pragma unroll
      for (int j = 0; j < 4; ++j) {
        int gr = grow_base + mm * 16 + j;
        float v = acc[mm][nn][j] + bi;
        if (EPI == 1) {
          v = v > 0.f ? v : 0.f;
          outb[(size_t)gr * N + gc] = __float2bfloat16(v);
        } else {
          size_t idx = (size_t)gr * N + gc;
          outf[idx] = outf[idx] + v;
        }
      }
    }
  }
}

// ---------------------------------------------------------------------------
extern "C" void kernel_launch(void* const* d_in, const int* in_sizes, int n_in,
                              void* d_out, int out_size, void* d_ws, size_t ws_size,
                              hipStream_t stream) {
  const float* x = (const float*)d_in[0];
  const float* ln1g = (const float*)d_in[1];
  const float* ln1b = (const float*)d_in[2];
  const float* ln2g = (const float*)d_in[3];
  const float* ln2b = (const float*)d_in[4];
  const float* W1 = (const float*)d_in[5];
  const float* b1 = (const float*)d_in[6];
  const float* W2 = (const float*)d_in[7];
  const float* b2 = (const float*)d_in[8];
  float* out = (float*)d_out;

  // Workspace layout (233,570,304 B):
  //   h:    [0, 65536000)              f32 [32000][512]   (LN1 out; dead after attn)
  //   h2b:  [0, 32768000)              bf16 (LN2 out; aliases dead h)
  //   hb:   [65536000, 98304000)       bf16 [32000][512]  (LN1 out bf16)
  //   hres: [98304000, 163840000)      f32 (attn out; dead after LN2)
  //   u:    [98304000, 229376000)      bf16 [32000][2048] (aliases dead hres)
  //   W1t:  [229376000, 231473152)     bf16 [2048][512]
  //   W2t:  [231473152, 233570304)     bf16 [512][2048]
  char* ws = (char*)d_ws;
  float* h = (float*)ws;
  __hip_bfloat16* h2b = (__hip_bfloat16*)ws;
  __hip_bfloat16* hb = (__hip_bfloat16*)(ws + 65536000);
  float* hres = (float*)(ws + 98304000);
  __hip_bfloat16* u = (__hip_bfloat16*)(ws + 98304000);
  __hip_bfloat16* W1t = (__hip_bfloat16*)(ws + 229376000);
  __hip_bfloat16* W2t = (__hip_bfloat16*)(ws + 231473152);

  transpose_bf16<<<dim3(D_FF / 32, D_MODEL / 32), dim3(32, 8), 0, stream>>>(
      W1, W1t, D_MODEL, D_FF);
  transpose_bf16<<<dim3(D_MODEL / 32, D_FF / 32), dim3(32, 8), 0, stream>>>(
      W2, W2t, D_FF, D_MODEL);

  ln_kernel<true><<<MROWS, 256, 0, stream>>>(x, ln1g, ln1b, h, hb);

  attn_mfma8<<<BATCH * N_HEADS, 512, 0, stream>>>(hb, h, hres);

  // h2 (f32) goes straight into d_out; GEMM2 accumulates on top of it.
  ln_kernel<true><<<MROWS, 256, 0, stream>>>(hres, ln2g, ln2b, out, h2b);

  // GEMM1: [32000,512] x [512,2048] -> u ; grid 125x8 = 1000 blocks (n-fast)
  gemm8p<1><<<(MROWS / 256) * (D_FF / 256), 512, 0, stream>>>(
      (const unsigned short*)h2b, (const unsigned short*)W1t, b1, nullptr, u,
      MROWS, D_FF, D_MODEL, D_FF / 256);
  // GEMM2: [32000,2048] x [2048,512] -> out (+=) ; grid 125x2 = 250 blocks
  gemm8p<2><<<(MROWS / 256) * (D_MODEL / 256), 512, 0, stream>>>(
      (const unsigned short*)u, (const unsigned short*)W2t, b2, out, nullptr,
      MROWS, D_MODEL, D_FF, D_MODEL / 256);
}

// Round 5
// 377.956 us; speedup vs baseline: 2.7878x; 1.0643x over previous
//
#include <hip/hip_runtime.h>
#include <hip/hip_bf16.h>

#define D_MODEL 512
#define N_HEADS 8
#define HDIM 64
#define D_FF 2048
#define BATCH 64
#define SEQ 500
#define MROWS (BATCH * SEQ)  // 32000

typedef __attribute__((ext_vector_type(8))) short bhalf8;   // 8 bf16 = 4 VGPRs
typedef __attribute__((ext_vector_type(4))) float floatx4;  // MFMA accumulator

#define AS_GLOBAL __attribute__((address_space(1)))
#define AS_LDS __attribute__((address_space(3)))

__device__ __forceinline__ void glds16(const void* g, void* l) {
  __builtin_amdgcn_global_load_lds((const AS_GLOBAL unsigned int*)g,
                                   (AS_LDS unsigned int*)l, 16, 0, 0);
}

__device__ __forceinline__ unsigned short f2bf(float f) {
  __hip_bfloat16 b = __float2bfloat16(f);
  return *reinterpret_cast<unsigned short*>(&b);
}

// ---------------------------------------------------------------------------
// LayerNorm: one block per row of 512. Optionally writes bf16 copy (for MFMA A).
// ---------------------------------------------------------------------------
template <bool WRITE_BF16>
__global__ __launch_bounds__(256) void ln_kernel(const float* __restrict__ x,
                                                 const float* __restrict__ g,
                                                 const float* __restrict__ b,
                                                 float* __restrict__ yf,
                                                 __hip_bfloat16* __restrict__ yb) {
  int row = blockIdx.x;
  int t = threadIdx.x;
  const float2* xp = (const float2*)(x + (size_t)row * D_MODEL);
  float2 v = xp[t];
  float s = v.x + v.y;
  float sq = v.x * v.x + v.y * v.y;
#pragma unroll
  for (int off = 32; off > 0; off >>= 1) {
    s += __shfl_down(s, off, 64);
    sq += __shfl_down(sq, off, 64);
  }
  __shared__ float red[8];
  if ((t & 63) == 0) {
    red[(t >> 6) * 2] = s;
    red[(t >> 6) * 2 + 1] = sq;
  }
  __syncthreads();
  s = red[0] + red[2] + red[4] + red[6];
  sq = red[1] + red[3] + red[5] + red[7];
  float mean = s * (1.0f / 512.0f);
  float var = sq * (1.0f / 512.0f) - mean * mean;
  float r = rsqrtf(var + 1e-6f);
  float2 gg = ((const float2*)g)[t];
  float2 bb = ((const float2*)b)[t];
  float y0 = (v.x - mean) * r * gg.x + bb.x;
  float y1 = (v.y - mean) * r * gg.y + bb.y;
  ((float2*)(yf + (size_t)row * D_MODEL))[t] = make_float2(y0, y1);
  if constexpr (WRITE_BF16) {
    __hip_bfloat162 bv2;
    bv2.x = __float2bfloat16(y0);
    bv2.y = __float2bfloat16(y1);
    ((__hip_bfloat162*)(yb + (size_t)row * D_MODEL))[t] = bv2;
  }
}

// ---------------------------------------------------------------------------
// Transpose + convert fp32 W[K][N] -> bf16 Wt[N][K] (LDS-tiled, 32x32)
// ---------------------------------------------------------------------------
__global__ __launch_bounds__(256) void transpose_bf16(const float* __restrict__ W,
                                                      __hip_bfloat16* __restrict__ Wt,
                                                      int K, int N) {
  __shared__ float tile[32][33];
  int n0 = blockIdx.x * 32, k0 = blockIdx.y * 32;
  int tx = threadIdx.x, ty = threadIdx.y;
#pragma unroll
  for (int j = 0; j < 32; j += 8)
    tile[ty + j][tx] = W[(size_t)(k0 + ty + j) * N + n0 + tx];
  __syncthreads();
#pragma unroll
  for (int j = 0; j < 32; j += 8)
    Wt[(size_t)(n0 + ty + j) * K + k0 + tx] = __float2bfloat16(tile[tx][ty + j]);
}

// ---------------------------------------------------------------------------
// Folded MFMA flash attention: one block per (b, head), 8 waves.
// q-tiles of 32 rows (16 tiles over 512-padded SEQ). Wave w owns the folded
// pair {15-w, w} -> exactly 9 kv-tile visits per wave (uniform causal load).
// K/V tiles (64 keys) staged once per block, double-buffered; K via glds16
// with XOR-swizzled source; V^T cooperative reg-staged transpose.
// ---------------------------------------------------------------------------
__device__ __forceinline__ void attn_tile_step(int jq, int kt, int fr, int kg,
                                               const char* Kb, const char* Vb,
                                               char* Pw, bhalf8 (&qf)[2][2],
                                               floatx4 (&O)[2][4],
                                               float (&m)[2][4], float (&l)[2][4]) {
  int roff = 32 * jq - 64 * kt;       // 0 or 32 when masking applies
  bool domask = (jq <= 2 * kt + 1);   // diagonal tiles only
#pragma unroll
  for (int mr = 0; mr < 2; ++mr) {
    floatx4 S[4];
#pragma unroll
    for (int nc = 0; nc < 4; ++nc) S[nc] = (floatx4){0.f, 0.f, 0.f, 0.f};
    __builtin_amdgcn_s_setprio(1);
#pragma unroll
    for (int kk = 0; kk < 2; ++kk) {
#pragma unroll
      for (int nc = 0; nc < 4; ++nc) {
        bhalf8 kf = *(const bhalf8*)(Kb + (nc * 16 + fr) * 128 +
                                     (((kk * 4 + kg) ^ (fr & 7)) << 4));
        S[nc] = __builtin_amdgcn_mfma_f32_16x16x32_bf16(qf[mr][kk], kf, S[nc], 0, 0, 0);
      }
    }
    __builtin_amdgcn_s_setprio(0);
    if (domask) {
#pragma unroll
      for (int nc = 0; nc < 4; ++nc)
#pragma unroll
        for (int j = 0; j < 4; ++j)
          if (nc * 16 + fr > roff + mr * 16 + kg * 4 + j) S[nc][j] = -INFINITY;
    }
    float mnew[4];
#pragma unroll
    for (int j = 0; j < 4; ++j)
      mnew[j] = fmaxf(fmaxf(S[0][j], S[1][j]), fmaxf(S[2][j], S[3][j]));
#pragma unroll
    for (int off = 1; off < 16; off <<= 1)
#pragma unroll
      for (int j = 0; j < 4; ++j) mnew[j] = fmaxf(mnew[j], __shfl_xor(mnew[j], off, 64));
#pragma unroll
    for (int j = 0; j < 4; ++j) {
      float mn = fmaxf(m[mr][j], mnew[j]);
      float sc = __expf((m[mr][j] - mn) * 0.125f);  // first tile: exp(-inf)=0
      m[mr][j] = mn;
      l[mr][j] *= sc;
#pragma unroll
      for (int nc = 0; nc < 4; ++nc) O[mr][nc][j] *= sc;
    }
    float p[4][4], rs[4];
#pragma unroll
    for (int j = 0; j < 4; ++j) rs[j] = 0.f;
#pragma unroll
    for (int nc = 0; nc < 4; ++nc)
#pragma unroll
      for (int j = 0; j < 4; ++j) {
        p[nc][j] = __expf((S[nc][j] - m[mr][j]) * 0.125f);  // masked -> 0
        rs[j] += p[nc][j];
      }
#pragma unroll
    for (int off = 1; off < 16; off <<= 1)
#pragma unroll
      for (int j = 0; j < 4; ++j) rs[j] += __shfl_xor(rs[j], off, 64);
#pragma unroll
    for (int j = 0; j < 4; ++j) l[mr][j] += rs[j];
#pragma unroll
    for (int nc = 0; nc < 4; ++nc)
#pragma unroll
      for (int j = 0; j < 4; ++j)
        *(unsigned short*)(Pw + ((kg * 4 + j) * 72 + nc * 16 + fr) * 2) = f2bf(p[nc][j]);
    __builtin_amdgcn_s_setprio(1);
#pragma unroll
    for (int kk = 0; kk < 2; ++kk) {
      bhalf8 pf = *(const bhalf8*)(Pw + fr * 144 + kk * 64 + kg * 16);
#pragma unroll
      for (int nc = 0; nc < 4; ++nc) {
        bhalf8 vf = *(const bhalf8*)(Vb + (nc * 16 + fr) * 144 + kk * 64 + kg * 16);
        O[mr][nc] = __builtin_amdgcn_mfma_f32_16x16x32_bf16(pf, vf, O[mr][nc], 0, 0, 0);
      }
    }
    __builtin_amdgcn_s_setprio(0);
  }
}

__global__ __launch_bounds__(512) void attn_fold(const __hip_bfloat16* __restrict__ hbp,
                                                 const float* __restrict__ h,
                                                 float* __restrict__ hres) {
  __shared__ unsigned short Ks[2][64 * 64];
  __shared__ unsigned short Vt[2][64 * 72];
  __shared__ unsigned short Ps[8][16 * 72];

  int blk = blockIdx.x;
  int b = blk >> 3, hd = blk & 7;
  int tid = threadIdx.x;
  int w = tid >> 6, lane = tid & 63;
  int fr = lane & 15, kg = lane >> 4;

  const unsigned short* hb = (const unsigned short*)hbp;
  size_t bbase = (size_t)b * SEQ * D_MODEL + hd * HDIM;

  int jH = 15 - w, jL = w;
  bhalf8 qH[2][2], qL[2][2];
#pragma unroll
  for (int mr = 0; mr < 2; ++mr) {
    int rH = 32 * jH + mr * 16 + fr;
    if (rH >= SEQ) rH = SEQ - 1;  // fake rows never written
    int rL = 32 * jL + mr * 16 + fr;
#pragma unroll
    for (int kk = 0; kk < 2; ++kk) {
      qH[mr][kk] = *(const bhalf8*)(hb + bbase + (size_t)rH * D_MODEL + kk * 32 + kg * 8);
      qL[mr][kk] = *(const bhalf8*)(hb + bbase + (size_t)rL * D_MODEL + kk * 32 + kg * 8);
    }
  }

  floatx4 OH[2][4], OL[2][4];
  float mH[2][4], lH[2][4], mL[2][4], lL[2][4];
#pragma unroll
  for (int mr = 0; mr < 2; ++mr)
#pragma unroll
    for (int nc = 0; nc < 4; ++nc) {
      OH[mr][nc] = (floatx4){0.f, 0.f, 0.f, 0.f};
      OL[mr][nc] = (floatx4){0.f, 0.f, 0.f, 0.f};
    }
#pragma unroll
  for (int mr = 0; mr < 2; ++mr)
#pragma unroll
    for (int j = 0; j < 4; ++j) {
      mH[mr][j] = -INFINITY; lH[mr][j] = 0.f;
      mL[mr][j] = -INFINITY; lL[mr][j] = 0.f;
    }

  int krow = w * 8 + (lane >> 3);
  int scb = (lane & 7) ^ (lane >> 3);

  {  // prologue: tile 0
    int sr = krow;  // < 64 <= SEQ
    glds16(hb + bbase + (size_t)sr * D_MODEL + scb * 8, (char*)Ks[0] + w * 1024);
    int vr = lane;
    bhalf8 v0 = *(const bhalf8*)(hb + bbase + (size_t)vr * D_MODEL + w * 8);
#pragma unroll
    for (int i = 0; i < 8; ++i) Vt[0][(w * 8 + i) * 72 + lane] = (unsigned short)v0[i];
  }
  __syncthreads();

  for (int kt = 0; kt < 8; ++kt) {
    int cur = kt & 1;
    bhalf8 vnext;
    if (kt < 7) {  // issue next tile's loads before compute
      int sr = (kt + 1) * 64 + krow;
      if (sr >= SEQ) sr = SEQ - 1;
      glds16(hb + bbase + (size_t)sr * D_MODEL + scb * 8, (char*)Ks[cur ^ 1] + w * 1024);
      int vr = (kt + 1) * 64 + lane;
      if (vr >= SEQ) vr = SEQ - 1;
      vnext = *(const bhalf8*)(hb + bbase + (size_t)vr * D_MODEL + w * 8);
    }

    const char* Kb = (const char*)Ks[cur];
    const char* Vb = (const char*)Vt[cur];
    char* Pw = (char*)Ps[w];
    if (jH >= 2 * kt) attn_tile_step(jH, kt, fr, kg, Kb, Vb, Pw, qH, OH, mH, lH);
    if (jL >= 2 * kt) attn_tile_step(jL, kt, fr, kg, Kb, Vb, Pw, qL, OL, mL, lL);

    if (kt < 7) {  // write-late V^T
#pragma unroll
      for (int i = 0; i < 8; ++i)
        Vt[cur ^ 1][(w * 8 + i) * 72 + lane] = (unsigned short)vnext[i];
    }
    __syncthreads();
  }

#pragma unroll
  for (int mr = 0; mr < 2; ++mr)
#pragma unroll
    for (int j = 0; j < 4; ++j) {
      int qH_row = 32 * jH + mr * 16 + kg * 4 + j;
      if (qH_row < SEQ) {
        float inv = 1.0f / lH[mr][j];
        size_t ro = bbase + (size_t)qH_row * D_MODEL;
#pragma unroll
        for (int nc = 0; nc < 4; ++nc) {
          size_t idx = ro + nc * 16 + fr;
          hres[idx] = h[idx] + OH[mr][nc][j] * inv;
        }
      }
      int qL_row = 32 * jL + mr * 16 + kg * 4 + j;
      {
        float inv = 1.0f / lL[mr][j];
        size_t ro = bbase + (size_t)qL_row * D_MODEL;
#pragma unroll
        for (int nc = 0; nc < 4; ++nc) {
          size_t idx = ro + nc * 16 + fr;
          hres[idx] = h[idx] + OL[mr][nc][j] * inv;
        }
      }
    }
}

// ---------------------------------------------------------------------------
// Pipelined bf16 MFMA GEMM: C = A[M,K] * Bt[N,K]^T.
// 128x256 tile, BK=32, 4 waves (wave = 128x64 out, 12 reads : 32 MFMA),
// 3-buffer ring (72 KiB LDS) -> 2 blocks/CU (cross-block TLP covers barrier
// stalls), stage 2 K-tiles ahead via glds16, counted vmcnt(6) once per tile.
// LDS rows 64B, swizzle s(r)=(r+(r>>2))&3 on the 16B slot: within every 8
// consecutive lanes all 8 bank-groups distinct (2 lanes/group over 16 = free).
// Applied on BOTH sides: pre-swizzled global source + swizzled ds_read.
// EPI==1: out_bf16 = relu(acc + bias)    EPI==2: out_f32 += acc + bias
// ---------------------------------------------------------------------------
template <int EPI>
__global__ __launch_bounds__(256, 2) void gemm128(const unsigned short* __restrict__ A,
                                                  const unsigned short* __restrict__ Bt,
                                                  const float* __restrict__ bias,
                                                  float* __restrict__ outf,
                                                  __hip_bfloat16* __restrict__ outb,
                                                  int M, int N, int K, int gx) {
  __shared__ __align__(16) char smem[3 * 24576];  // buf: A[128][64B] 8K | B[256][64B] 16K

  // bijective XCD-chunked swizzle (m204), n-fast linearization
  int nwg = gridDim.x;
  int bid = blockIdx.x;
  int q = nwg >> 3, r = nwg & 7;
  int xcd = bid & 7, lo = bid >> 3;
  int wg = (xcd < r ? xcd * (q + 1) : r * (q + 1) + (xcd - r) * q) + lo;
  int by = wg / gx, bx = wg % gx;
  int m0 = by * 128, n0 = bx * 256;

  int tid = threadIdx.x;
  int w = tid >> 6, lane = tid & 63;
  int fr = lane & 15, kg = lane >> 4;

  // --- staging addressing: per thread 2 A-glds + 4 B-glds per K-tile
  int lr = lane >> 2;  // row within 16-row chunk
  int scol = (((lane & 3) ^ (((lane >> 2) + (lane >> 4)) & 3)) << 3);  // pre-swizzled
  const unsigned short* Asrc0 = A + (size_t)(m0 + w * 16 + lr) * K + scol;
  const unsigned short* Asrc1 = A + (size_t)(m0 + (w + 4) * 16 + lr) * K + scol;
  const unsigned short* Bsrc0 = Bt + (size_t)(n0 + w * 16 + lr) * K + scol;
  const unsigned short* Bsrc1 = Bt + (size_t)(n0 + (w + 4) * 16 + lr) * K + scol;
  const unsigned short* Bsrc2 = Bt + (size_t)(n0 + (w + 8) * 16 + lr) * K + scol;
  const unsigned short* Bsrc3 = Bt + (size_t)(n0 + (w + 12) * 16 + lr) * K + scol;
  int dA0 = w * 1024, dA1 = (w + 4) * 1024;
  int dB0 = 8192 + w * 1024, dB1 = 8192 + (w + 4) * 1024;
  int dB2 = 8192 + (w + 8) * 1024, dB3 = 8192 + (w + 12) * 1024;

  // --- fragment read addressing (swizzled slot)
  int slot = ((kg ^ ((fr + (fr >> 2)) & 3)) << 4);
  int aoff = fr * 64 + slot;                        // + mm*1024
  int boff = 8192 + w * 4096 + fr * 64 + slot;      // + nn*1024

  floatx4 acc[8][4];
#pragma unroll
  for (int i = 0; i < 8; ++i)
#pragma unroll
    for (int j = 0; j < 4; ++j) acc[i][j] = (floatx4){0.f, 0.f, 0.f, 0.f};

  int nt = K >> 5;

#define STAGE_A(t, buf)                              \
  {                                                  \
    char* d = smem + (buf) * 24576;                  \
    glds16(Asrc0 + (t) * 32, d + dA0);               \
    glds16(Asrc1 + (t) * 32, d + dA1);               \
  }
#define STAGE_B(t, buf)                              \
  {                                                  \
    char* d = smem + (buf) * 24576;                  \
    glds16(Bsrc0 + (t) * 32, d + dB0);               \
    glds16(Bsrc1 + (t) * 32, d + dB1);               \
    glds16(Bsrc2 + (t) * 32, d + dB2);               \
    glds16(Bsrc3 + (t) * 32, d + dB3);               \
  }

  // prologue: tiles 0,1 in flight; retire tile 0 before first read
  STAGE_A(0, 0); STAGE_B(0, 0);
  STAGE_A(1, 1); STAGE_B(1, 1);
  asm volatile("s_waitcnt vmcnt(6)" ::: "memory");
  __builtin_amdgcn_s_barrier();

  int bufc = 0;
  for (int t = 0; t < nt; ++t) {
    const char* bufp = smem + bufc * 24576;
    int bufn = bufc + 2;
    if (bufn >= 3) bufn -= 3;
    bhalf8 afr[4], bfr[4];

    // ---- phase 0: rows 0..63, load all B frags
#pragma unroll
    for (int nn = 0; nn < 4; ++nn)
      bfr[nn] = *(const bhalf8*)(bufp + boff + nn * 1024);
#pragma unroll
    for (int ml = 0; ml < 4; ++ml)
      afr[ml] = *(const bhalf8*)(bufp + aoff + ml * 1024);
    if (t + 2 < nt) STAGE_A(t + 2, bufn);
    __builtin_amdgcn_s_barrier();
    __builtin_amdgcn_s_setprio(1);
#pragma unroll
    for (int ml = 0; ml < 4; ++ml)
#pragma unroll
      for (int nn = 0; nn < 4; ++nn)
        acc[ml][nn] =
            __builtin_amdgcn_mfma_f32_16x16x32_bf16(afr[ml], bfr[nn], acc[ml][nn], 0, 0, 0);
    __builtin_amdgcn_s_setprio(0);
    __builtin_amdgcn_s_barrier();

    // ---- phase 1: rows 64..127, B frags reused
#pragma unroll
    for (int ml = 0; ml < 4; ++ml)
      afr[ml] = *(const bhalf8*)(bufp + aoff + (4 + ml) * 1024);
    if (t + 2 < nt) STAGE_B(t + 2, bufn);
    __builtin_amdgcn_s_barrier();
    __builtin_amdgcn_s_setprio(1);
#pragma unroll
    for (int ml = 0; ml < 4; ++ml)
#pragma unroll
      for (int nn = 0; nn < 4; ++nn)
        acc[4 + ml][nn] =
            __builtin_amdgcn_mfma_f32_16x16x32_bf16(afr[ml], bfr[nn], acc[4 + ml][nn], 0, 0, 0);
    __builtin_amdgcn_s_setprio(0);
    // counted wait: retire tile t+1's 6 loads (per-wave wait before barrier
    // propagates the guarantee block-wide). Tail drains to 0.
    if (t < nt - 2)
      asm volatile("s_waitcnt vmcnt(6)" ::: "memory");
    else
      asm volatile("s_waitcnt vmcnt(0)" ::: "memory");
    __builtin_amdgcn_s_barrier();
    bufc = bufc + 1 == 3 ? 0 : bufc + 1;
  }
#undef STAGE_A
#undef STAGE_B

  // epilogue: C/D layout col=fr, row=kg*4+j (verified m89/m91)
  int grow_base = m0 + kg * 4;
  int gcol_base = n0 + w * 64 + fr;
#pragma unroll
  for (int mm = 0; mm < 8; ++mm) {
#pragma unroll
    for (int nn = 0; nn < 4; ++nn) {
      int gc = gcol_base + nn * 16;
      float bi = bias[gc];
#pragma unroll
      for (int j = 0; j < 4; ++j) {
        int gr = grow_base + mm * 16 + j;
        float v = acc[mm][nn][j] + bi;
        if (EPI == 1) {
          v = v > 0.f ? v : 0.f;
          outb[(size_t)gr * N + gc] = __float2bfloat16(v);
        } else {
          size_t idx = (size_t)gr * N + gc;
          outf[idx] = outf[idx] + v;
        }
      }
    }
  }
}

// ---------------------------------------------------------------------------
extern "C" void kernel_launch(void* const* d_in, const int* in_sizes, int n_in,
                              void* d_out, int out_size, void* d_ws, size_t ws_size,
                              hipStream_t stream) {
  const float* x = (const float*)d_in[0];
  const float* ln1g = (const float*)d_in[1];
  const float* ln1b = (const float*)d_in[2];
  const float* ln2g = (const float*)d_in[3];
  const float* ln2b = (const float*)d_in[4];
  const float* W1 = (const float*)d_in[5];
  const float* b1 = (const float*)d_in[6];
  const float* W2 = (const float*)d_in[7];
  const float* b2 = (const float*)d_in[8];
  float* out = (float*)d_out;

  // Workspace layout (233,570,304 B):
  //   h:    [0, 65536000)              f32 [32000][512]   (LN1 out; dead after attn)
  //   h2b:  [0, 32768000)              bf16 (LN2 out; aliases dead h)
  //   hb:   [65536000, 98304000)       bf16 [32000][512]  (LN1 out bf16)
  //   hres: [98304000, 163840000)      f32 (attn out; dead after LN2)
  //   u:    [98304000, 229376000)      bf16 [32000][2048] (aliases dead hres)
  //   W1t:  [229376000, 231473152)     bf16 [2048][512]
  //   W2t:  [231473152, 233570304)     bf16 [512][2048]
  char* ws = (char*)d_ws;
  float* h = (float*)ws;
  __hip_bfloat16* h2b = (__hip_bfloat16*)ws;
  __hip_bfloat16* hb = (__hip_bfloat16*)(ws + 65536000);
  float* hres = (float*)(ws + 98304000);
  __hip_bfloat16* u = (__hip_bfloat16*)(ws + 98304000);
  __hip_bfloat16* W1t = (__hip_bfloat16*)(ws + 229376000);
  __hip_bfloat16* W2t = (__hip_bfloat16*)(ws + 231473152);

  transpose_bf16<<<dim3(D_FF / 32, D_MODEL / 32), dim3(32, 8), 0, stream>>>(
      W1, W1t, D_MODEL, D_FF);
  transpose_bf16<<<dim3(D_MODEL / 32, D_FF / 32), dim3(32, 8), 0, stream>>>(
      W2, W2t, D_FF, D_MODEL);

  ln_kernel<true><<<MROWS, 256, 0, stream>>>(x, ln1g, ln1b, h, hb);

  attn_fold<<<BATCH * N_HEADS, 512, 0, stream>>>(hb, h, hres);

  // h2 (f32) goes straight into d_out; GEMM2 accumulates on top of it.
  ln_kernel<true><<<MROWS, 256, 0, stream>>>(hres, ln2g, ln2b, out, h2b);

  // GEMM1: [32000,512] x [512,2048] -> u ; grid 250x8 = 2000 blocks
  gemm128<1><<<(MROWS / 128) * (D_FF / 256), 256, 0, stream>>>(
      (const unsigned short*)h2b, (const unsigned short*)W1t, b1, nullptr, u,
      MROWS, D_FF, D_MODEL, D_FF / 256);
  // GEMM2: [32000,2048] x [2048,512] -> out (+=) ; grid 250x2 = 500 blocks
  gemm128<2><<<(MROWS / 128) * (D_MODEL / 256), 256, 0, stream>>>(
      (const unsigned short*)u, (const unsigned short*)W2t, b2, out, nullptr,
      MROWS, D_MODEL, D_FF, D_MODEL / 256);
}